// Round 1
// baseline (296.189 us; speedup 1.0000x reference)
//
#include <hip/hip_runtime.h>

// Problem constants (B, L, D, H) = (16, 512, 128, 8)
#define B_  16
#define L_  512
#define D_  128
#define H_  8
#define HD_ 1024   // H*D
#define NH_ 128    // H*B
#define M_  8192   // B*L

typedef unsigned short u16;
typedef __attribute__((ext_vector_type(8))) short s16x8;   // 8 bf16 = 4 VGPRs
typedef __attribute__((ext_vector_type(4))) float f32x4;   // MFMA accumulator

// ---------- bf16 helpers (raw ushort representation) ----------
__device__ __forceinline__ float bf2f(u16 u) {
    union { unsigned u; float f; } x; x.u = ((unsigned)u) << 16; return x.f;
}
__device__ __forceinline__ u16 f2bf(float f) {
    unsigned u = __float_as_uint(f);
    return (u16)((u + 0x7FFFu + ((u >> 16) & 1u)) >> 16);   // RNE
}

// ---------------------------------------------------------------
// MFMA bt-core: C(64x64) = A(64xK) @ B(64xK)^T for one wave.
// A, B row-major with leading dims lda/ldb; caller pre-offsets to the
// wave's row/col origin.  Fragment layout (m89/m120-verified):
//   A/B operand: row = lane&15, k = (lane>>4)*8 + j  (16B contiguous)
//   C/D:         col = lane&15, row = (lane>>4)*4 + reg
// ---------------------------------------------------------------
__device__ __forceinline__ void mfma_bt64(const u16* __restrict__ A, int lda,
                                          const u16* __restrict__ B, int ldb,
                                          int K, int lane, f32x4 acc[4][4]) {
    const int mr = lane & 15, quad = lane >> 4;
    for (int k0 = 0; k0 < K; k0 += 32) {
        s16x8 av[4], bv[4];
#pragma unroll
        for (int i = 0; i < 4; i++)
            av[i] = *(const s16x8*)(A + (size_t)(i * 16 + mr) * lda + k0 + quad * 8);
#pragma unroll
        for (int j = 0; j < 4; j++)
            bv[j] = *(const s16x8*)(B + (size_t)(j * 16 + mr) * ldb + k0 + quad * 8);
#pragma unroll
        for (int i = 0; i < 4; i++)
#pragma unroll
            for (int j = 0; j < 4; j++)
                acc[i][j] = __builtin_amdgcn_mfma_f32_16x16x32_bf16(av[i], bv[j], acc[i][j], 0, 0, 0);
    }
}

// ---------------------------------------------------------------
// K0: detect float dtype (fp32 vs packed bf16) + mask dtype (i32 vs u8).
// ---------------------------------------------------------------
__global__ void k0_detect(const unsigned int* __restrict__ pad,
                          const unsigned int* __restrict__ xw,
                          int* __restrict__ flags) {
    __shared__ int sMask, sCnt;
    if (threadIdx.x == 0) { sMask = 0; sCnt = 0; }
    __syncthreads();
    int bad = 0;
#pragma unroll
    for (int i = 0; i < 4; i++) {
        unsigned u = pad[threadIdx.x * 4 + i];
        bad |= (u > 1u) ? 1 : 0;
    }
    int cnt = 0;
#pragma unroll
    for (int i = 0; i < 16; i++) {
        unsigned w = xw[threadIdx.x * 16 + i];
        unsigned e = (w >> 7) & 0xFFu;
        cnt += (e >= 100u && e <= 131u) ? 1 : 0;
    }
    if (bad) atomicOr(&sMask, 1);
    atomicAdd(&sCnt, cnt);
    __syncthreads();
    if (threadIdx.x == 0) {
        flags[0] = (sCnt > 2048) ? 1 : 0;   // 1 => floats are bf16
        flags[1] = sMask;                   // 1 => mask is uint8
    }
}

// ---------------------------------------------------------------
// Kprep_conv: normalize all float inputs to bf16 in ws (copy or convert).
// ---------------------------------------------------------------
#define PREP_TOT 1576064
__global__ __launch_bounds__(256) void kprep_conv(
    const void* x, const void* Wq, const void* bq, const void* Wk, const void* bk,
    const void* Wv, const void* bv, const void* Wo, const void* bo,
    const int* __restrict__ flags,
    u16* xb, u16* Wqb, u16* Wkb, u16* Wvb, u16* Wob,
    u16* bqb, u16* bkb, u16* bvb, u16* bob) {
    int gid = blockIdx.x * 256 + threadIdx.x;
    if (gid >= PREP_TOT) return;
    const int dt = flags[0];
    const void* src; u16* dst; int off;
    if      (gid < 1048576) { src = x;  dst = xb;  off = gid; }
    else if (gid < 1179648) { src = Wq; dst = Wqb; off = gid - 1048576; }
    else if (gid < 1310720) { src = Wk; dst = Wkb; off = gid - 1179648; }
    else if (gid < 1441792) { src = Wv; dst = Wvb; off = gid - 1310720; }
    else if (gid < 1572864) { src = Wo; dst = Wob; off = gid - 1441792; }
    else if (gid < 1573888) { src = bq; dst = bqb; off = gid - 1572864; }
    else if (gid < 1574912) { src = bk; dst = bkb; off = gid - 1573888; }
    else if (gid < 1575936) { src = bv; dst = bvb; off = gid - 1574912; }
    else                    { src = bo; dst = bob; off = gid - 1575936; }
    dst[off] = dt ? ((const u16*)src)[off] : f2bf(((const float*)src)[off]);
}

// ---------------------------------------------------------------
// Kprep_mask: pack pad_mask into bitmask [16][512][16 u32 words].
// Also zeroes the colsum accumulator (65536 floats) for k2_colsum.
// ---------------------------------------------------------------
__global__ __launch_bounds__(256) void kprep_mask(const void* __restrict__ pad,
                                                  const int* __restrict__ flags,
                                                  unsigned* __restrict__ mb,
                                                  float* __restrict__ colsum) {
    int w = blockIdx.x * 256 + threadIdx.x;     // < 131072
    if (w < NH_ * L_) colsum[w] = 0.0f;         // 65536 floats
    size_t base = (size_t)w * 32;
    unsigned m = 0;
    if (flags[1]) {
        const unsigned char* p = (const unsigned char*)pad;
#pragma unroll
        for (int b = 0; b < 32; b++) m |= (p[base + b] ? 1u : 0u) << b;
    } else {
        const int* p = (const int*)pad;
#pragma unroll
        for (int b = 0; b < 32; b++) m |= (p[base + b] ? 1u : 0u) << b;
    }
    mb[w] = m;
}

// ---------------------------------------------------------------
// K1: QKV projection via MFMA.  y = x @ W^T + b.
// q,k written head-major [n=h*16+bb][l][d]; v written TRANSPOSED [n][d][l].
// grid (8 e-tiles(=head), 64 m-tiles, 3), 256 threads.
// ---------------------------------------------------------------
__global__ __launch_bounds__(256) void k1_proj(
    const u16* __restrict__ xb,
    const u16* __restrict__ Wqb, const u16* __restrict__ Wkb, const u16* __restrict__ Wvb,
    const u16* __restrict__ bqb, const u16* __restrict__ bkb, const u16* __restrict__ bvb,
    u16* __restrict__ qb, u16* __restrict__ kb, u16* __restrict__ vtb) {
    const int h  = blockIdx.x;           // e-tile == head (128 e per head)
    const int m0 = blockIdx.y * 128;
    const int z  = blockIdx.z;
    const u16* W    = (z == 0) ? Wqb : (z == 1) ? Wkb : Wvb;
    const u16* bias = (z == 0) ? bqb : (z == 1) ? bkb : bvb;

    const int lane = threadIdx.x & 63, wave = threadIdx.x >> 6;
    const int wr = wave >> 1, wc = wave & 1;
    const int mr = lane & 15, quad = lane >> 4;

    f32x4 acc[4][4];
#pragma unroll
    for (int i = 0; i < 4; i++)
#pragma unroll
        for (int j = 0; j < 4; j++) acc[i][j] = (f32x4){0.f, 0.f, 0.f, 0.f};

    mfma_bt64(xb + (size_t)(m0 + wr * 64) * D_, D_,
              W + (size_t)(h * 128 + wc * 64) * D_, D_, D_, lane, acc);

    __shared__ __align__(16) u16 T[128][144];
#pragma unroll
    for (int i = 0; i < 4; i++)
#pragma unroll
        for (int j = 0; j < 4; j++) {
            int col = wc * 64 + j * 16 + mr;
            float bv_ = bf2f(bias[h * 128 + col]);
#pragma unroll
            for (int r = 0; r < 4; r++)
                T[wr * 64 + i * 16 + quad * 4 + r][col] = f2bf(acc[i][j][r] + bv_);
        }
    __syncthreads();

    const int bb = m0 >> 9, l0 = m0 & 511;
    const int t = threadIdx.x;
    if (z < 2) {
        u16* out = z ? kb : qb;
        int row = t >> 1, c0 = (t & 1) * 64;
        u16* dst = out + ((size_t)(h * B_ + bb) * L_ + l0 + row) * D_ + c0;
#pragma unroll
        for (int c = 0; c < 64; c += 8)
            *(uint4*)(dst + c) = *(const uint4*)&T[row][c0 + c];
    } else {
        int d = t >> 1, lc0 = (t & 1) * 64;
        u16* dst = vtb + ((size_t)(h * B_ + bb) * D_ + d) * L_ + l0 + lc0;
#pragma unroll
        for (int c = 0; c < 64; c += 8) {
            u16 tmp[8];
#pragma unroll
            for (int s = 0; s < 8; s++) tmp[s] = T[lc0 + c + s][d];
            *(uint4*)(dst + c) = *(const uint4*)tmp;
        }
    }
}

// ---------------------------------------------------------------
// K2: column sums only — NO score materialization.
// colsum[n,k] = sum_q exp((mask? -inf : q.k) * rs), via fp32 atomics.
// grid (16 = 4qt*4kt, 128 n), 256 threads, no LDS => 4 blocks/CU.
// ---------------------------------------------------------------
__global__ __launch_bounds__(256) void k2_colsum(
    const u16* __restrict__ qb, const u16* __restrict__ kb,
    const unsigned* __restrict__ mbits,
    float* __restrict__ colsum) {
    const int qt = blockIdx.x >> 2, kt = blockIdx.x & 3;
    const int n  = blockIdx.y;
    const int bb = n & (B_ - 1);
    const int lane = threadIdx.x & 63, wave = threadIdx.x >> 6;
    const int wr = wave >> 1, wc = wave & 1;
    const int mr = lane & 15, quad = lane >> 4;
    const float rs = 0.08838834764831845f;   // 1/sqrt(128)

    f32x4 acc[4][4];
#pragma unroll
    for (int i = 0; i < 4; i++)
#pragma unroll
        for (int j = 0; j < 4; j++) acc[i][j] = (f32x4){0.f, 0.f, 0.f, 0.f};

    // identical operand decomposition to k4_fused => bit-identical e values
    mfma_bt64(qb + (size_t)n * L_ * D_ + (size_t)(qt * 128 + wr * 64) * D_, D_,
              kb + (size_t)n * L_ * D_ + (size_t)(kt * 128 + wc * 64) * D_, D_,
              D_, lane, acc);

    float cs[4] = {0.f, 0.f, 0.f, 0.f};
#pragma unroll
    for (int j = 0; j < 4; j++) {
        int kc = kt * 128 + wc * 64 + j * 16 + mr;
#pragma unroll
        for (int i = 0; i < 4; i++)
#pragma unroll
            for (int r = 0; r < 4; r++) {
                int q = qt * 128 + wr * 64 + i * 16 + quad * 4 + r;
                unsigned w = mbits[((size_t)(bb << 9) + q) * 16 + (kc >> 5)];
                float e = ((w >> (kc & 31)) & 1u) ? 0.f : __expf(acc[i][j][r] * rs);
                cs[j] += e;
            }
    }
    // reduce over the 4 quads (same column within the wave)
#pragma unroll
    for (int j = 0; j < 4; j++) {
        cs[j] += __shfl_xor(cs[j], 16);
        cs[j] += __shfl_xor(cs[j], 32);
    }
    if (quad == 0) {
#pragma unroll
        for (int j = 0; j < 4; j++)
            atomicAdd(&colsum[(size_t)n * L_ + kt * 128 + wc * 64 + j * 16 + mr], cs[j]);
    }
}

// ---------------------------------------------------------------
// K4: fused scores+softmax+AV.  Per 128-k chunk: recompute QK^T
// (bit-identical to k2_colsum), e = exp(s*rs)/colsum (linv folded into e
// — replaces the old k3 v-scale), stage e chunk in LDS, MFMA against V^T.
// att[n,q,d] written at the end (aliases qb: block writes exactly the
// q-rows only it read, after a barrier).  grid (4 q-tiles, 128 n).
// ---------------------------------------------------------------
__global__ __launch_bounds__(256) void k4_fused(
    const u16* __restrict__ qb, const u16* __restrict__ kb,
    const u16* __restrict__ vtb, const unsigned* __restrict__ mbits,
    const float* __restrict__ colsum,
    u16* __restrict__ att) {
    const int qt = blockIdx.x;           // 0..3
    const int n  = blockIdx.y;           // 0..127
    const int bb = n & (B_ - 1);
    const int lane = threadIdx.x & 63, wave = threadIdx.x >> 6;
    const int wr = wave >> 1, wc = wave & 1;
    const int mr = lane & 15, quad = lane >> 4;
    const float rs = 0.08838834764831845f;

    // ld = 136: 4-way write aliasing (vs 8-way at 144); 136%8==0 keeps
    // 16B alignment for the s16x8 fragment reads.
    __shared__ __align__(16) u16 E[128][136];

    const u16* Aq = qb + (size_t)n * L_ * D_ + (size_t)(qt * 128 + wr * 64) * D_;
    const u16* Vt = vtb + (size_t)n * D_ * L_;   // [d][k]

    f32x4 acc_o[4][4];
#pragma unroll
    for (int i = 0; i < 4; i++)
#pragma unroll
        for (int j = 0; j < 4; j++) acc_o[i][j] = (f32x4){0.f, 0.f, 0.f, 0.f};

#pragma unroll 1
    for (int kt = 0; kt < 4; kt++) {
        f32x4 acc_s[4][4];
#pragma unroll
        for (int i = 0; i < 4; i++)
#pragma unroll
            for (int j = 0; j < 4; j++) acc_s[i][j] = (f32x4){0.f, 0.f, 0.f, 0.f};

        mfma_bt64(Aq, D_,
                  kb + (size_t)n * L_ * D_ + (size_t)(kt * 128 + wc * 64) * D_, D_,
                  D_, lane, acc_s);

        // mask + exp + fold 1/colsum, store e chunk to LDS
#pragma unroll
        for (int j = 0; j < 4; j++) {
            int kc = kt * 128 + wc * 64 + j * 16 + mr;
            float li = 1.0f / colsum[(size_t)n * L_ + kc];
#pragma unroll
            for (int i = 0; i < 4; i++)
#pragma unroll
                for (int r = 0; r < 4; r++) {
                    int ql = wr * 64 + i * 16 + quad * 4 + r;
                    int q  = qt * 128 + ql;
                    unsigned w = mbits[((size_t)(bb << 9) + q) * 16 + (kc >> 5)];
                    float e = ((w >> (kc & 31)) & 1u) ? 0.f
                              : __expf(acc_s[i][j][r] * rs) * li;
                    E[ql][wc * 64 + j * 16 + mr] = f2bf(e);
                }
        }
        __syncthreads();

        // AV: acc_o += E[q][k] @ Vt[d][kt*128+k]^T  (both k-contiguous)
#pragma unroll
        for (int k0 = 0; k0 < 128; k0 += 32) {
            s16x8 av[4], bv[4];
#pragma unroll
            for (int i = 0; i < 4; i++)
                av[i] = *(const s16x8*)&E[wr * 64 + i * 16 + mr][k0 + quad * 8];
#pragma unroll
            for (int j = 0; j < 4; j++)
                bv[j] = *(const s16x8*)(Vt + (size_t)(wc * 64 + j * 16 + mr) * L_
                                        + kt * 128 + k0 + quad * 8);
#pragma unroll
            for (int i = 0; i < 4; i++)
#pragma unroll
                for (int j = 0; j < 4; j++)
                    acc_o[i][j] = __builtin_amdgcn_mfma_f32_16x16x32_bf16(av[i], bv[j], acc_o[i][j], 0, 0, 0);
        }
        __syncthreads();   // E reused next kt (and as the epilogue buffer)
    }

    // epilogue: transpose through LDS (reuse E) and store att rows
#pragma unroll
    for (int i = 0; i < 4; i++)
#pragma unroll
        for (int j = 0; j < 4; j++)
#pragma unroll
            for (int r = 0; r < 4; r++)
                E[wr * 64 + i * 16 + quad * 4 + r][wc * 64 + j * 16 + mr] = f2bf(acc_o[i][j][r]);
    __syncthreads();
    int t = threadIdx.x, row = t >> 1, c0 = (t & 1) * 64;
    u16* dst = att + ((size_t)n * L_ + qt * 128 + row) * D_ + c0;
#pragma unroll
    for (int c = 0; c < 64; c += 8)
        *(uint4*)(dst + c) = *(const uint4*)&E[row][c0 + c];
}

// ---------------------------------------------------------------
// K5: out = att_flat[8192][1024] @ Wo[128][1024]^T + bo.
// BM=64, BN=128, 2 waves (128 threads), grid 128.  dt-switched output.
// ---------------------------------------------------------------
__global__ __launch_bounds__(128) void k5_out(
    const u16* __restrict__ att, const u16* __restrict__ Wob,
    const u16* __restrict__ bob, const int* __restrict__ flags,
    void* __restrict__ out) {
    const int dt = flags[0];
    const int m0 = blockIdx.x * 64;
    const int lane = threadIdx.x & 63, wc = threadIdx.x >> 6;
    const int mr = lane & 15, quad = lane >> 4;

    f32x4 acc[4][4];
#pragma unroll
    for (int i = 0; i < 4; i++)
#pragma unroll
        for (int j = 0; j < 4; j++) acc[i][j] = (f32x4){0.f, 0.f, 0.f, 0.f};

    mfma_bt64(att + (size_t)m0 * HD_, HD_,
              Wob + (size_t)(wc * 64) * HD_, HD_, HD_, lane, acc);

    __shared__ __align__(16) float Tf[64][132];
#pragma unroll
    for (int i = 0; i < 4; i++)
#pragma unroll
        for (int j = 0; j < 4; j++) {
            int col = wc * 64 + j * 16 + mr;
            float bv_ = bf2f(bob[col]);
#pragma unroll
            for (int r = 0; r < 4; r++)
                Tf[i * 16 + quad * 4 + r][col] = acc[i][j][r] + bv_;
        }
    __syncthreads();
    int t = threadIdx.x, row = t >> 1, c0 = (t & 1) * 64;
    size_t base = (size_t)(m0 + row) * D_ + c0;
    if (dt) {
        u16* o = (u16*)out;
#pragma unroll
        for (int c = 0; c < 64; c += 8) {
            u16 tmp[8];
#pragma unroll
            for (int s = 0; s < 8; s++) tmp[s] = f2bf(Tf[row][c0 + c + s]);
            *(uint4*)(o + base + c) = *(const uint4*)tmp;
        }
    } else {
        float* o = (float*)out;
#pragma unroll
        for (int c = 0; c < 64; c += 4)
            *(float4*)(o + base + c) = *(const float4*)&Tf[row][c0 + c];
    }
}

// ---------------------------------------------------------------
extern "C" void kernel_launch(void* const* d_in, const int* in_sizes, int n_in,
                              void* d_out, int out_size, void* d_ws, size_t ws_size,
                              hipStream_t stream) {
    (void)in_sizes; (void)n_in; (void)out_size; (void)ws_size;
    const void* x  = d_in[0];
    const void* Wq = d_in[1]; const void* bq = d_in[2];
    const void* Wk = d_in[3]; const void* bk = d_in[4];
    const void* Wv = d_in[5]; const void* bv = d_in[6];
    const void* Wo = d_in[7]; const void* bo = d_in[8];
    const void* pad = d_in[9];

    char* p = (char*)d_ws;
    auto alloc = [&](size_t bytes) { char* r = p; p += (bytes + 255) & ~(size_t)255; return r; };
    int*  flags = (int*)alloc(256);
    u16*  xb   = (u16*)alloc(2097152);
    u16*  Wqb  = (u16*)alloc(262144);
    u16*  Wkb  = (u16*)alloc(262144);
    u16*  Wvb  = (u16*)alloc(262144);
    u16*  Wob  = (u16*)alloc(262144);
    u16*  bqb  = (u16*)alloc(2048);
    u16*  bkb  = (u16*)alloc(2048);
    u16*  bvb  = (u16*)alloc(2048);
    u16*  bob  = (u16*)alloc(256);
    unsigned* mbits = (unsigned*)alloc(524288);
    float* colsum = (float*)alloc(262144);    // [128 n][512 k] fp32
    u16*  qb   = (u16*)alloc(16777216);
    u16*  kb   = (u16*)alloc(16777216);
    u16*  vtb  = (u16*)alloc(16777216);
    u16*  att  = qb;   // alias: k4_fused writes att only to the q-rows it owns

    k0_detect<<<1, 256, 0, stream>>>((const unsigned*)pad, (const unsigned*)x, flags);
    kprep_conv<<<(PREP_TOT + 255) / 256, 256, 0, stream>>>(
        x, Wq, bq, Wk, bk, Wv, bv, Wo, bo, flags,
        xb, Wqb, Wkb, Wvb, Wob, bqb, bkb, bvb, bob);
    kprep_mask<<<512, 256, 0, stream>>>(pad, flags, mbits, colsum);
    k1_proj<<<dim3(8, 64, 3), 256, 0, stream>>>(
        xb, Wqb, Wkb, Wvb, bqb, bkb, bvb, qb, kb, vtb);
    k2_colsum<<<dim3(16, NH_), 256, 0, stream>>>(qb, kb, mbits, colsum);
    k4_fused<<<dim3(4, NH_), 256, 0, stream>>>(qb, kb, vtb, mbits, colsum, att);
    k5_out<<<128, 128, 0, stream>>>(att, Wob, bob, flags, d_out);
}

// Round 2
// 275.625 us; speedup vs baseline: 1.0746x; 1.0746x over previous
//
#include <hip/hip_runtime.h>

// Problem constants (B, L, D, H) = (16, 512, 128, 8)
#define B_  16
#define L_  512
#define D_  128
#define H_  8
#define HD_ 1024   // H*D
#define NH_ 128    // H*B
#define M_  8192   // B*L

typedef unsigned short u16;
typedef __attribute__((ext_vector_type(8))) short s16x8;   // 8 bf16 = 4 VGPRs
typedef __attribute__((ext_vector_type(4))) float f32x4;   // MFMA accumulator

// ---------- bf16 helpers (raw ushort representation) ----------
__device__ __forceinline__ float bf2f(u16 u) {
    union { unsigned u; float f; } x; x.u = ((unsigned)u) << 16; return x.f;
}
__device__ __forceinline__ u16 f2bf(float f) {
    unsigned u = __float_as_uint(f);
    return (u16)((u + 0x7FFFu + ((u >> 16) & 1u)) >> 16);   // RNE
}

// ---------------------------------------------------------------
// MFMA bt-core: C(64x64) = A(64xK) @ B(64xK)^T for one wave.
// A, B row-major with leading dims lda/ldb; caller pre-offsets to the
// wave's row/col origin.  Fragment layout (m89/m120-verified):
//   A/B operand: row = lane&15, k = (lane>>4)*8 + j  (16B contiguous)
//   C/D:         col = lane&15, row = (lane>>4)*4 + reg
// ---------------------------------------------------------------
__device__ __forceinline__ void mfma_bt64(const u16* __restrict__ A, int lda,
                                          const u16* __restrict__ B, int ldb,
                                          int K, int lane, f32x4 acc[4][4]) {
    const int mr = lane & 15, quad = lane >> 4;
    for (int k0 = 0; k0 < K; k0 += 32) {
        s16x8 av[4], bv[4];
#pragma unroll
        for (int i = 0; i < 4; i++)
            av[i] = *(const s16x8*)(A + (size_t)(i * 16 + mr) * lda + k0 + quad * 8);
#pragma unroll
        for (int j = 0; j < 4; j++)
            bv[j] = *(const s16x8*)(B + (size_t)(j * 16 + mr) * ldb + k0 + quad * 8);
#pragma unroll
        for (int i = 0; i < 4; i++)
#pragma unroll
            for (int j = 0; j < 4; j++)
                acc[i][j] = __builtin_amdgcn_mfma_f32_16x16x32_bf16(av[i], bv[j], acc[i][j], 0, 0, 0);
    }
}

// ---------------------------------------------------------------
// K0: detect float dtype (fp32 vs packed bf16) + mask dtype (i32 vs u8).
// ---------------------------------------------------------------
__global__ void k0_detect(const unsigned int* __restrict__ pad,
                          const unsigned int* __restrict__ xw,
                          int* __restrict__ flags) {
    __shared__ int sMask, sCnt;
    if (threadIdx.x == 0) { sMask = 0; sCnt = 0; }
    __syncthreads();
    int bad = 0;
#pragma unroll
    for (int i = 0; i < 4; i++) {
        unsigned u = pad[threadIdx.x * 4 + i];
        bad |= (u > 1u) ? 1 : 0;
    }
    int cnt = 0;
#pragma unroll
    for (int i = 0; i < 16; i++) {
        unsigned w = xw[threadIdx.x * 16 + i];
        unsigned e = (w >> 7) & 0xFFu;
        cnt += (e >= 100u && e <= 131u) ? 1 : 0;
    }
    if (bad) atomicOr(&sMask, 1);
    atomicAdd(&sCnt, cnt);
    __syncthreads();
    if (threadIdx.x == 0) {
        flags[0] = (sCnt > 2048) ? 1 : 0;   // 1 => floats are bf16
        flags[1] = sMask;                   // 1 => mask is uint8
    }
}

// ---------------------------------------------------------------
// Kprep_conv: normalize all float inputs to bf16 in ws (copy or convert).
// ---------------------------------------------------------------
#define PREP_TOT 1576064
__global__ __launch_bounds__(256) void kprep_conv(
    const void* x, const void* Wq, const void* bq, const void* Wk, const void* bk,
    const void* Wv, const void* bv, const void* Wo, const void* bo,
    const int* __restrict__ flags,
    u16* xb, u16* Wqb, u16* Wkb, u16* Wvb, u16* Wob,
    u16* bqb, u16* bkb, u16* bvb, u16* bob) {
    int gid = blockIdx.x * 256 + threadIdx.x;
    if (gid >= PREP_TOT) return;
    const int dt = flags[0];
    const void* src; u16* dst; int off;
    if      (gid < 1048576) { src = x;  dst = xb;  off = gid; }
    else if (gid < 1179648) { src = Wq; dst = Wqb; off = gid - 1048576; }
    else if (gid < 1310720) { src = Wk; dst = Wkb; off = gid - 1179648; }
    else if (gid < 1441792) { src = Wv; dst = Wvb; off = gid - 1310720; }
    else if (gid < 1572864) { src = Wo; dst = Wob; off = gid - 1441792; }
    else if (gid < 1573888) { src = bq; dst = bqb; off = gid - 1572864; }
    else if (gid < 1574912) { src = bk; dst = bkb; off = gid - 1573888; }
    else if (gid < 1575936) { src = bv; dst = bvb; off = gid - 1574912; }
    else                    { src = bo; dst = bob; off = gid - 1575936; }
    dst[off] = dt ? ((const u16*)src)[off] : f2bf(((const float*)src)[off]);
}

// ---------------------------------------------------------------
// Kprep_mask: pack pad_mask into bitmask [16][512][16 u32 words].
// Also zeroes the colsum accumulator (65536 floats) for k2_scores.
// ---------------------------------------------------------------
__global__ __launch_bounds__(256) void kprep_mask(const void* __restrict__ pad,
                                                  const int* __restrict__ flags,
                                                  unsigned* __restrict__ mb,
                                                  float* __restrict__ colsum) {
    int w = blockIdx.x * 256 + threadIdx.x;     // < 131072
    if (w < NH_ * L_) colsum[w] = 0.0f;         // 65536 floats
    size_t base = (size_t)w * 32;
    unsigned m = 0;
    if (flags[1]) {
        const unsigned char* p = (const unsigned char*)pad;
#pragma unroll
        for (int b = 0; b < 32; b++) m |= (p[base + b] ? 1u : 0u) << b;
    } else {
        const int* p = (const int*)pad;
#pragma unroll
        for (int b = 0; b < 32; b++) m |= (p[base + b] ? 1u : 0u) << b;
    }
    mb[w] = m;
}

// ---------------------------------------------------------------
// K1: QKV projection via MFMA.  y = x @ W^T + b.
// q,k written head-major [n=h*16+bb][l][d]; v written TRANSPOSED [n][d][l].
// grid (8 e-tiles(=head), 64 m-tiles, 3), 256 threads.
// ---------------------------------------------------------------
__global__ __launch_bounds__(256) void k1_proj(
    const u16* __restrict__ xb,
    const u16* __restrict__ Wqb, const u16* __restrict__ Wkb, const u16* __restrict__ Wvb,
    const u16* __restrict__ bqb, const u16* __restrict__ bkb, const u16* __restrict__ bvb,
    u16* __restrict__ qb, u16* __restrict__ kb, u16* __restrict__ vtb) {
    const int h  = blockIdx.x;           // e-tile == head (128 e per head)
    const int m0 = blockIdx.y * 128;
    const int z  = blockIdx.z;
    const u16* W    = (z == 0) ? Wqb : (z == 1) ? Wkb : Wvb;
    const u16* bias = (z == 0) ? bqb : (z == 1) ? bkb : bvb;

    const int lane = threadIdx.x & 63, wave = threadIdx.x >> 6;
    const int wr = wave >> 1, wc = wave & 1;
    const int mr = lane & 15, quad = lane >> 4;

    f32x4 acc[4][4];
#pragma unroll
    for (int i = 0; i < 4; i++)
#pragma unroll
        for (int j = 0; j < 4; j++) acc[i][j] = (f32x4){0.f, 0.f, 0.f, 0.f};

    mfma_bt64(xb + (size_t)(m0 + wr * 64) * D_, D_,
              W + (size_t)(h * 128 + wc * 64) * D_, D_, D_, lane, acc);

    __shared__ __align__(16) u16 T[128][144];
#pragma unroll
    for (int i = 0; i < 4; i++)
#pragma unroll
        for (int j = 0; j < 4; j++) {
            int col = wc * 64 + j * 16 + mr;
            float bv_ = bf2f(bias[h * 128 + col]);
#pragma unroll
            for (int r = 0; r < 4; r++)
                T[wr * 64 + i * 16 + quad * 4 + r][col] = f2bf(acc[i][j][r] + bv_);
        }
    __syncthreads();

    const int bb = m0 >> 9, l0 = m0 & 511;
    const int t = threadIdx.x;
    if (z < 2) {
        u16* out = z ? kb : qb;
        int row = t >> 1, c0 = (t & 1) * 64;
        u16* dst = out + ((size_t)(h * B_ + bb) * L_ + l0 + row) * D_ + c0;
#pragma unroll
        for (int c = 0; c < 64; c += 8)
            *(uint4*)(dst + c) = *(const uint4*)&T[row][c0 + c];
    } else {
        int d = t >> 1, lc0 = (t & 1) * 64;
        u16* dst = vtb + ((size_t)(h * B_ + bb) * D_ + d) * L_ + l0 + lc0;
#pragma unroll
        for (int c = 0; c < 64; c += 8) {
            u16 tmp[8];
#pragma unroll
            for (int s = 0; s < 8; s++) tmp[s] = T[lc0 + c + s][d];
            *(uint4*)(dst + c) = *(const uint4*)tmp;
        }
    }
}

// ---------------------------------------------------------------
// K2: e-tile (128q x 128k) per block + pre-reduced colsum atomics.
// grid (16 = qt*4+kt, 128 n), 256 threads, 4 waves (2x2).
// Mask words staged in LDS (hidden under MFMA) -> no per-element
// global mask loads.  Occupancy cap 50% (was 19% at 512 blocks).
// ---------------------------------------------------------------
__global__ __launch_bounds__(256, 4) void k2_scores(
    const u16* __restrict__ qb, const u16* __restrict__ kb,
    const unsigned* __restrict__ mbits,
    u16* __restrict__ sb, float* __restrict__ colsum) {
    const int qt = blockIdx.x >> 2, kt = blockIdx.x & 3;
    const int n  = blockIdx.y;
    const int bb = n & (B_ - 1);
    const int lane = threadIdx.x & 63, wave = threadIdx.x >> 6;
    const int wr = wave >> 1, wc = wave & 1;
    const int mr = lane & 15, quad = lane >> 4;
    const float rs = 0.08838834764831845f;   // 1/sqrt(128)

    __shared__ __align__(16) u16 T[128][136];
    __shared__ float CS[2][128];
    __shared__ unsigned MW[128][4];

    // stage this block's mask words: 128 q-rows x 4 dwords (2KB)
    {
        int t = threadIdx.x;
        int q = t >> 1, w2 = (t & 1) * 2;
        const unsigned* src = mbits + ((size_t)(bb << 9) + qt * 128 + q) * 16 + kt * 4 + w2;
        uint2 v = *(const uint2*)src;
        MW[q][w2] = v.x; MW[q][w2 + 1] = v.y;
    }

    f32x4 acc[4][4];
#pragma unroll
    for (int i = 0; i < 4; i++)
#pragma unroll
        for (int j = 0; j < 4; j++) acc[i][j] = (f32x4){0.f, 0.f, 0.f, 0.f};

    mfma_bt64(qb + ((size_t)n * L_ + qt * 128 + wr * 64) * D_, D_,
              kb + ((size_t)n * L_ + kt * 128 + wc * 64) * D_, D_, D_, lane, acc);
    __syncthreads();   // MW visible (latency hidden under MFMA)

    float cs[4] = {0.f, 0.f, 0.f, 0.f};
#pragma unroll
    for (int j = 0; j < 4; j++) {
        const int wsel = wc * 2 + (j >> 1);
        const int bit  = ((j & 1) << 4) + mr;
#pragma unroll
        for (int i = 0; i < 4; i++)
#pragma unroll
            for (int r = 0; r < 4; r++) {
                int ql = wr * 64 + i * 16 + quad * 4 + r;
                unsigned w = MW[ql][wsel];
                float e = ((w >> bit) & 1u) ? 0.f : __expf(acc[i][j][r] * rs);
                cs[j] += e;
                T[ql][wc * 64 + j * 16 + mr] = f2bf(e);
            }
    }
    // reduce over the 4 quads (same column within the wave)
#pragma unroll
    for (int j = 0; j < 4; j++) {
        cs[j] += __shfl_xor(cs[j], 16);
        cs[j] += __shfl_xor(cs[j], 32);
    }
    if (quad == 0) {
#pragma unroll
        for (int j = 0; j < 4; j++) CS[wr][wc * 64 + j * 16 + mr] = cs[j];
    }
    __syncthreads();
    // coalesced e-store
    {
        int t = threadIdx.x, row = t >> 1, c0 = (t & 1) * 64;
        u16* dst = sb + ((size_t)n * L_ + qt * 128 + row) * L_ + kt * 128 + c0;
#pragma unroll
        for (int c = 0; c < 64; c += 8)
            *(uint4*)(dst + c) = *(const uint4*)&T[row][c0 + c];
    }
    // one atomic per column per block (4 blocks contribute per column)
    if (threadIdx.x < 128)
        atomicAdd(&colsum[(size_t)n * L_ + kt * 128 + threadIdx.x],
                  CS[0][threadIdx.x] + CS[1][threadIdx.x]);
}

// ---------------------------------------------------------------
// K3: fold softmax normalization into V^T:  vt[n][d][k] /= colsum[n][k].
// 8 elements/thread, grid 4096 x 256.
// ---------------------------------------------------------------
__global__ __launch_bounds__(256) void k3_vscale(u16* __restrict__ vtb,
                                                 const float* __restrict__ colsum) {
    int idx = blockIdx.x * 256 + threadIdx.x;      // < 1048576
    int n = idx >> 13;                             // 8192 groups per n
    int rem = idx & 8191;
    int d = rem >> 6;
    int kg = (rem & 63) << 3;
    u16* p = vtb + ((size_t)n * D_ + d) * L_ + kg;
    uint4 v = *(const uint4*)p;
    float cv[8];
    *(float4*)&cv[0] = *(const float4*)(colsum + (size_t)n * L_ + kg);
    *(float4*)&cv[4] = *(const float4*)(colsum + (size_t)n * L_ + kg + 4);
    u16* u = (u16*)&v;
#pragma unroll
    for (int s = 0; s < 8; s++) u[s] = f2bf(bf2f(u[s]) / cv[s]);
    *(uint4*)p = v;
}

// ---------------------------------------------------------------
// K4: att[n,q,d] = sum_k e[q,k] * vt'[d,k]  (both row-major in k).
// grid (8 q-tiles of 64, 128 n), 256 threads, 4 waves (2x2),
// wave tile 32q x 64d (acc[2][4]).  att aliases qb.
// ---------------------------------------------------------------
__global__ __launch_bounds__(256, 4) void k4_av(
    const u16* __restrict__ sb, const u16* __restrict__ vtb,
    u16* __restrict__ att) {
    const int q0 = blockIdx.x * 64;
    const int n  = blockIdx.y;
    const int lane = threadIdx.x & 63, wave = threadIdx.x >> 6;
    const int wr = wave >> 1, wc = wave & 1;
    const int mr = lane & 15, quad = lane >> 4;

    f32x4 acc[2][4];
#pragma unroll
    for (int i = 0; i < 2; i++)
#pragma unroll
        for (int j = 0; j < 4; j++) acc[i][j] = (f32x4){0.f, 0.f, 0.f, 0.f};

    const u16* A  = sb  + ((size_t)n * L_ + q0 + wr * 32) * L_;
    const u16* Bb = vtb + ((size_t)n * D_ + wc * 64) * L_;

    for (int k0 = 0; k0 < L_; k0 += 32) {
        s16x8 av[2], bv[4];
#pragma unroll
        for (int i = 0; i < 2; i++)
            av[i] = *(const s16x8*)(A + (size_t)(i * 16 + mr) * L_ + k0 + quad * 8);
#pragma unroll
        for (int j = 0; j < 4; j++)
            bv[j] = *(const s16x8*)(Bb + (size_t)(j * 16 + mr) * L_ + k0 + quad * 8);
#pragma unroll
        for (int i = 0; i < 2; i++)
#pragma unroll
            for (int j = 0; j < 4; j++)
                acc[i][j] = __builtin_amdgcn_mfma_f32_16x16x32_bf16(av[i], bv[j], acc[i][j], 0, 0, 0);
    }

    __shared__ __align__(16) u16 T[64][136];
#pragma unroll
    for (int i = 0; i < 2; i++)
#pragma unroll
        for (int j = 0; j < 4; j++)
#pragma unroll
            for (int r = 0; r < 4; r++)
                T[wr * 32 + i * 16 + quad * 4 + r][wc * 64 + j * 16 + mr] = f2bf(acc[i][j][r]);
    __syncthreads();
    int t = threadIdx.x, row = t >> 2, c0 = (t & 3) * 32;
    u16* dst = att + ((size_t)n * L_ + q0 + row) * D_ + c0;
#pragma unroll
    for (int c = 0; c < 32; c += 8)
        *(uint4*)(dst + c) = *(const uint4*)&T[row][c0 + c];
}

// ---------------------------------------------------------------
// K5: out = att_flat[8192][1024] @ Wo[128][1024]^T + bo.
// BM=64, BN=128, 2 waves (128 threads), grid 128.  dt-switched output.
// ---------------------------------------------------------------
__global__ __launch_bounds__(128) void k5_out(
    const u16* __restrict__ att, const u16* __restrict__ Wob,
    const u16* __restrict__ bob, const int* __restrict__ flags,
    void* __restrict__ out) {
    const int dt = flags[0];
    const int m0 = blockIdx.x * 64;
    const int lane = threadIdx.x & 63, wc = threadIdx.x >> 6;
    const int mr = lane & 15, quad = lane >> 4;

    f32x4 acc[4][4];
#pragma unroll
    for (int i = 0; i < 4; i++)
#pragma unroll
        for (int j = 0; j < 4; j++) acc[i][j] = (f32x4){0.f, 0.f, 0.f, 0.f};

    mfma_bt64(att + (size_t)m0 * HD_, HD_,
              Wob + (size_t)(wc * 64) * HD_, HD_, HD_, lane, acc);

    __shared__ __align__(16) float Tf[64][132];
#pragma unroll
    for (int i = 0; i < 4; i++)
#pragma unroll
        for (int j = 0; j < 4; j++) {
            int col = wc * 64 + j * 16 + mr;
            float bv_ = bf2f(bob[col]);
#pragma unroll
            for (int r = 0; r < 4; r++)
                Tf[i * 16 + quad * 4 + r][col] = acc[i][j][r] + bv_;
        }
    __syncthreads();
    int t = threadIdx.x, row = t >> 1, c0 = (t & 1) * 64;
    size_t base = (size_t)(m0 + row) * D_ + c0;
    if (dt) {
        u16* o = (u16*)out;
#pragma unroll
        for (int c = 0; c < 64; c += 8) {
            u16 tmp[8];
#pragma unroll
            for (int s = 0; s < 8; s++) tmp[s] = f2bf(Tf[row][c0 + c + s]);
            *(uint4*)(o + base + c) = *(const uint4*)tmp;
        }
    } else {
        float* o = (float*)out;
#pragma unroll
        for (int c = 0; c < 64; c += 4)
            *(float4*)(o + base + c) = *(const float4*)&Tf[row][c0 + c];
    }
}

// ---------------------------------------------------------------
extern "C" void kernel_launch(void* const* d_in, const int* in_sizes, int n_in,
                              void* d_out, int out_size, void* d_ws, size_t ws_size,
                              hipStream_t stream) {
    (void)in_sizes; (void)n_in; (void)out_size; (void)ws_size;
    const void* x  = d_in[0];
    const void* Wq = d_in[1]; const void* bq = d_in[2];
    const void* Wk = d_in[3]; const void* bk = d_in[4];
    const void* Wv = d_in[5]; const void* bv = d_in[6];
    const void* Wo = d_in[7]; const void* bo = d_in[8];
    const void* pad = d_in[9];

    char* p = (char*)d_ws;
    auto alloc = [&](size_t bytes) { char* r = p; p += (bytes + 255) & ~(size_t)255; return r; };
    int*  flags = (int*)alloc(256);
    u16*  xb   = (u16*)alloc(2097152);
    u16*  Wqb  = (u16*)alloc(262144);
    u16*  Wkb  = (u16*)alloc(262144);
    u16*  Wvb  = (u16*)alloc(262144);
    u16*  Wob  = (u16*)alloc(262144);
    u16*  bqb  = (u16*)alloc(2048);
    u16*  bkb  = (u16*)alloc(2048);
    u16*  bvb  = (u16*)alloc(2048);
    u16*  bob  = (u16*)alloc(256);
    unsigned* mbits = (unsigned*)alloc(524288);
    float* colsum = (float*)alloc(262144);    // [128 n][512 k] fp32
    u16*  qb   = (u16*)alloc(16777216);
    u16*  kb   = (u16*)alloc(16777216);
    u16*  vtb  = (u16*)alloc(16777216);
    u16*  sb   = (u16*)alloc(67108864);
    u16*  att  = qb;   // alias: qb dead after k2; k4 writes disjoint q-rows

    k0_detect<<<1, 256, 0, stream>>>((const unsigned*)pad, (const unsigned*)x, flags);
    kprep_conv<<<(PREP_TOT + 255) / 256, 256, 0, stream>>>(
        x, Wq, bq, Wk, bk, Wv, bv, Wo, bo, flags,
        xb, Wqb, Wkb, Wvb, Wob, bqb, bkb, bvb, bob);
    kprep_mask<<<512, 256, 0, stream>>>(pad, flags, mbits, colsum);
    k1_proj<<<dim3(8, 64, 3), 256, 0, stream>>>(
        xb, Wqb, Wkb, Wvb, bqb, bkb, bvb, qb, kb, vtb);
    k2_scores<<<dim3(16, NH_), 256, 0, stream>>>(qb, kb, mbits, sb, colsum);
    k3_vscale<<<4096, 256, 0, stream>>>(vtb, colsum);
    k4_av<<<dim3(8, NH_), 256, 0, stream>>>(sb, vtb, att);
    k5_out<<<128, 128, 0, stream>>>(att, Wob, bob, flags, d_out);
}

// Round 3
// 253.410 us; speedup vs baseline: 1.1688x; 1.0877x over previous
//
#include <hip/hip_runtime.h>

// Problem constants (B, L, D, H) = (16, 512, 128, 8)
#define B_  16
#define L_  512
#define D_  128
#define H_  8
#define HD_ 1024   // H*D
#define NH_ 128    // H*B
#define M_  8192   // B*L

typedef unsigned short u16;
typedef __attribute__((ext_vector_type(8))) short s16x8;   // 8 bf16 = 4 VGPRs
typedef __attribute__((ext_vector_type(4))) float f32x4;   // MFMA accumulator

// ---------- bf16 helpers (raw ushort representation) ----------
__device__ __forceinline__ float bf2f(u16 u) {
    union { unsigned u; float f; } x; x.u = ((unsigned)u) << 16; return x.f;
}
__device__ __forceinline__ u16 f2bf(float f) {
    unsigned u = __float_as_uint(f);
    return (u16)((u + 0x7FFFu + ((u >> 16) & 1u)) >> 16);   // RNE
}

// ---------------------------------------------------------------
// MFMA bt-core: C(64x64) = A(64xK) @ B(64xK)^T for one wave.
// Fragment layout (m89/m120-verified):
//   A/B operand: row = lane&15, k = (lane>>4)*8 + j  (16B contiguous)
//   C/D:         col = lane&15, row = (lane>>4)*4 + reg
// ---------------------------------------------------------------
__device__ __forceinline__ void mfma_bt64(const u16* __restrict__ A, int lda,
                                          const u16* __restrict__ B, int ldb,
                                          int K, int lane, f32x4 acc[4][4]) {
    const int mr = lane & 15, quad = lane >> 4;
    for (int k0 = 0; k0 < K; k0 += 32) {
        s16x8 av[4], bv[4];
#pragma unroll
        for (int i = 0; i < 4; i++)
            av[i] = *(const s16x8*)(A + (size_t)(i * 16 + mr) * lda + k0 + quad * 8);
#pragma unroll
        for (int j = 0; j < 4; j++)
            bv[j] = *(const s16x8*)(B + (size_t)(j * 16 + mr) * ldb + k0 + quad * 8);
#pragma unroll
        for (int i = 0; i < 4; i++)
#pragma unroll
            for (int j = 0; j < 4; j++)
                acc[i][j] = __builtin_amdgcn_mfma_f32_16x16x32_bf16(av[i], bv[j], acc[i][j], 0, 0, 0);
    }
}

// ---------------------------------------------------------------
// K0: detect float dtype (fp32 vs packed bf16) + mask dtype (i32 vs u8).
// ---------------------------------------------------------------
__global__ void k0_detect(const unsigned int* __restrict__ pad,
                          const unsigned int* __restrict__ xw,
                          int* __restrict__ flags) {
    __shared__ int sMask, sCnt;
    if (threadIdx.x == 0) { sMask = 0; sCnt = 0; }
    __syncthreads();
    int bad = 0;
#pragma unroll
    for (int i = 0; i < 4; i++) {
        unsigned u = pad[threadIdx.x * 4 + i];
        bad |= (u > 1u) ? 1 : 0;
    }
    int cnt = 0;
#pragma unroll
    for (int i = 0; i < 16; i++) {
        unsigned w = xw[threadIdx.x * 16 + i];
        unsigned e = (w >> 7) & 0xFFu;
        cnt += (e >= 100u && e <= 131u) ? 1 : 0;
    }
    if (bad) atomicOr(&sMask, 1);
    atomicAdd(&sCnt, cnt);
    __syncthreads();
    if (threadIdx.x == 0) {
        flags[0] = (sCnt > 2048) ? 1 : 0;   // 1 => floats are bf16
        flags[1] = sMask;                   // 1 => mask is uint8
    }
}

// ---------------------------------------------------------------
// Kprep_conv: normalize all float inputs to bf16 in ws (copy or convert).
// ---------------------------------------------------------------
#define PREP_TOT 1576064
__global__ __launch_bounds__(256) void kprep_conv(
    const void* x, const void* Wq, const void* bq, const void* Wk, const void* bk,
    const void* Wv, const void* bv, const void* Wo, const void* bo,
    const int* __restrict__ flags,
    u16* xb, u16* Wqb, u16* Wkb, u16* Wvb, u16* Wob,
    u16* bqb, u16* bkb, u16* bvb, u16* bob) {
    int gid = blockIdx.x * 256 + threadIdx.x;
    if (gid >= PREP_TOT) return;
    const int dt = flags[0];
    const void* src; u16* dst; int off;
    if      (gid < 1048576) { src = x;  dst = xb;  off = gid; }
    else if (gid < 1179648) { src = Wq; dst = Wqb; off = gid - 1048576; }
    else if (gid < 1310720) { src = Wk; dst = Wkb; off = gid - 1179648; }
    else if (gid < 1441792) { src = Wv; dst = Wvb; off = gid - 1310720; }
    else if (gid < 1572864) { src = Wo; dst = Wob; off = gid - 1441792; }
    else if (gid < 1573888) { src = bq; dst = bqb; off = gid - 1572864; }
    else if (gid < 1574912) { src = bk; dst = bkb; off = gid - 1573888; }
    else if (gid < 1575936) { src = bv; dst = bvb; off = gid - 1574912; }
    else                    { src = bo; dst = bob; off = gid - 1575936; }
    dst[off] = dt ? ((const u16*)src)[off] : f2bf(((const float*)src)[off]);
}

// ---------------------------------------------------------------
// Kprep_mask: pack pad_mask into bitmask [16][512][16 u32 words].
// Vectorized (uint4) loads; also zeroes colsum for k2_scores.
// ---------------------------------------------------------------
__global__ __launch_bounds__(256) void kprep_mask(const void* __restrict__ pad,
                                                  const int* __restrict__ flags,
                                                  unsigned* __restrict__ mb,
                                                  float* __restrict__ colsum) {
    int w = blockIdx.x * 256 + threadIdx.x;     // < 131072
    if (w < NH_ * L_) colsum[w] = 0.0f;         // 65536 floats
    unsigned m = 0;
    if (flags[1]) {                              // uint8 mask: 32 B = 2 uint4
        const uint4* p = (const uint4*)pad + (size_t)w * 2;
        uint4 a = p[0], b = p[1];
        unsigned ws[8] = {a.x, a.y, a.z, a.w, b.x, b.y, b.z, b.w};
#pragma unroll
        for (int i = 0; i < 8; i++) {
            unsigned v = ws[i];
            m |= ((v & 0xFFu)        ? 1u : 0u) << (i * 4)
               | ((v & 0xFF00u)     ? 1u : 0u) << (i * 4 + 1)
               | ((v & 0xFF0000u)   ? 1u : 0u) << (i * 4 + 2)
               | ((v & 0xFF000000u) ? 1u : 0u) << (i * 4 + 3);
        }
    } else {                                     // int32 mask: 128 B = 8 uint4
        const uint4* p = (const uint4*)pad + (size_t)w * 8;
#pragma unroll
        for (int i = 0; i < 8; i++) {
            uint4 v = p[i];
            m |= (v.x ? 1u : 0u) << (i * 4)
               | (v.y ? 1u : 0u) << (i * 4 + 1)
               | (v.z ? 1u : 0u) << (i * 4 + 2)
               | (v.w ? 1u : 0u) << (i * 4 + 3);
        }
    }
    mb[w] = m;
}

// ---------------------------------------------------------------
// K1: QKV projection via MFMA.  y = x @ W^T + b.
// q,k written head-major [n=h*16+bb][l][d]; v written TRANSPOSED [n][d][l].
// grid (8 e-tiles(=head), 64 m-tiles, 3), 256 threads.
// ---------------------------------------------------------------
__global__ __launch_bounds__(256) void k1_proj(
    const u16* __restrict__ xb,
    const u16* __restrict__ Wqb, const u16* __restrict__ Wkb, const u16* __restrict__ Wvb,
    const u16* __restrict__ bqb, const u16* __restrict__ bkb, const u16* __restrict__ bvb,
    u16* __restrict__ qb, u16* __restrict__ kb, u16* __restrict__ vtb) {
    const int h  = blockIdx.x;           // e-tile == head (128 e per head)
    const int m0 = blockIdx.y * 128;
    const int z  = blockIdx.z;
    const u16* W    = (z == 0) ? Wqb : (z == 1) ? Wkb : Wvb;
    const u16* bias = (z == 0) ? bqb : (z == 1) ? bkb : bvb;

    const int lane = threadIdx.x & 63, wave = threadIdx.x >> 6;
    const int wr = wave >> 1, wc = wave & 1;
    const int mr = lane & 15, quad = lane >> 4;

    f32x4 acc[4][4];
#pragma unroll
    for (int i = 0; i < 4; i++)
#pragma unroll
        for (int j = 0; j < 4; j++) acc[i][j] = (f32x4){0.f, 0.f, 0.f, 0.f};

    mfma_bt64(xb + (size_t)(m0 + wr * 64) * D_, D_,
              W + (size_t)(h * 128 + wc * 64) * D_, D_, D_, lane, acc);

    __shared__ __align__(16) u16 T[128][144];
#pragma unroll
    for (int i = 0; i < 4; i++)
#pragma unroll
        for (int j = 0; j < 4; j++) {
            int col = wc * 64 + j * 16 + mr;
            float bv_ = bf2f(bias[h * 128 + col]);
#pragma unroll
            for (int r = 0; r < 4; r++)
                T[wr * 64 + i * 16 + quad * 4 + r][col] = f2bf(acc[i][j][r] + bv_);
        }
    __syncthreads();

    const int bb = m0 >> 9, l0 = m0 & 511;
    const int t = threadIdx.x;
    if (z < 2) {
        u16* out = z ? kb : qb;
        int row = t >> 1, c0 = (t & 1) * 64;
        u16* dst = out + ((size_t)(h * B_ + bb) * L_ + l0 + row) * D_ + c0;
#pragma unroll
        for (int c = 0; c < 64; c += 8)
            *(uint4*)(dst + c) = *(const uint4*)&T[row][c0 + c];
    } else {
        int d = t >> 1, lc0 = (t & 1) * 64;
        u16* dst = vtb + ((size_t)(h * B_ + bb) * D_ + d) * L_ + l0 + lc0;
#pragma unroll
        for (int c = 0; c < 64; c += 8) {
            u16 tmp[8];
#pragma unroll
            for (int s = 0; s < 8; s++) tmp[s] = T[lc0 + c + s][d];
            *(uint4*)(dst + c) = *(const uint4*)tmp;
        }
    }
}

// ---------------------------------------------------------------
// K2: e-tile (128q x 128k) per block + pre-reduced colsum atomics.
// grid (16 = qt*4+kt, 128 n), 256 threads, 4 waves (2x2).
// ---------------------------------------------------------------
__global__ __launch_bounds__(256, 4) void k2_scores(
    const u16* __restrict__ qb, const u16* __restrict__ kb,
    const unsigned* __restrict__ mbits,
    u16* __restrict__ sb, float* __restrict__ colsum) {
    const int qt = blockIdx.x >> 2, kt = blockIdx.x & 3;
    const int n  = blockIdx.y;
    const int bb = n & (B_ - 1);
    const int lane = threadIdx.x & 63, wave = threadIdx.x >> 6;
    const int wr = wave >> 1, wc = wave & 1;
    const int mr = lane & 15, quad = lane >> 4;
    const float rs = 0.08838834764831845f;   // 1/sqrt(128)

    __shared__ __align__(16) u16 T[128][136];
    __shared__ float CS[2][128];
    __shared__ unsigned MW[128][4];

    // stage this block's mask words: 128 q-rows x 4 dwords (2KB)
    {
        int t = threadIdx.x;
        int q = t >> 1, w2 = (t & 1) * 2;
        const unsigned* src = mbits + ((size_t)(bb << 9) + qt * 128 + q) * 16 + kt * 4 + w2;
        uint2 v = *(const uint2*)src;
        MW[q][w2] = v.x; MW[q][w2 + 1] = v.y;
    }

    f32x4 acc[4][4];
#pragma unroll
    for (int i = 0; i < 4; i++)
#pragma unroll
        for (int j = 0; j < 4; j++) acc[i][j] = (f32x4){0.f, 0.f, 0.f, 0.f};

    mfma_bt64(qb + ((size_t)n * L_ + qt * 128 + wr * 64) * D_, D_,
              kb + ((size_t)n * L_ + kt * 128 + wc * 64) * D_, D_, D_, lane, acc);
    __syncthreads();   // MW visible (latency hidden under MFMA)

    float cs[4] = {0.f, 0.f, 0.f, 0.f};
#pragma unroll
    for (int j = 0; j < 4; j++) {
        const int wsel = wc * 2 + (j >> 1);
        const int bit  = ((j & 1) << 4) + mr;
#pragma unroll
        for (int i = 0; i < 4; i++)
#pragma unroll
            for (int r = 0; r < 4; r++) {
                int ql = wr * 64 + i * 16 + quad * 4 + r;
                unsigned w = MW[ql][wsel];
                float e = ((w >> bit) & 1u) ? 0.f : __expf(acc[i][j][r] * rs);
                cs[j] += e;
                T[ql][wc * 64 + j * 16 + mr] = f2bf(e);
            }
    }
    // reduce over the 4 quads (same column within the wave)
#pragma unroll
    for (int j = 0; j < 4; j++) {
        cs[j] += __shfl_xor(cs[j], 16);
        cs[j] += __shfl_xor(cs[j], 32);
    }
    if (quad == 0) {
#pragma unroll
        for (int j = 0; j < 4; j++) CS[wr][wc * 64 + j * 16 + mr] = cs[j];
    }
    __syncthreads();
    // coalesced e-store
    {
        int t = threadIdx.x, row = t >> 1, c0 = (t & 1) * 64;
        u16* dst = sb + ((size_t)n * L_ + qt * 128 + row) * L_ + kt * 128 + c0;
#pragma unroll
        for (int c = 0; c < 64; c += 8)
            *(uint4*)(dst + c) = *(const uint4*)&T[row][c0 + c];
    }
    // one atomic per column per block (4 blocks contribute per column)
    if (threadIdx.x < 128)
        atomicAdd(&colsum[(size_t)n * L_ + kt * 128 + threadIdx.x],
                  CS[0][threadIdx.x] + CS[1][threadIdx.x]);
}

// ---------------------------------------------------------------
// K3: fold softmax normalization into V^T:  vt[n][d][k] /= colsum[n][k].
// 8 elements/thread, grid 4096 x 256.
// ---------------------------------------------------------------
__global__ __launch_bounds__(256) void k3_vscale(u16* __restrict__ vtb,
                                                 const float* __restrict__ colsum) {
    int idx = blockIdx.x * 256 + threadIdx.x;      // < 1048576
    int n = idx >> 13;                             // 8192 groups per n
    int rem = idx & 8191;
    int d = rem >> 6;
    int kg = (rem & 63) << 3;
    u16* p = vtb + ((size_t)n * D_ + d) * L_ + kg;
    uint4 v = *(const uint4*)p;
    float cv[8];
    *(float4*)&cv[0] = *(const float4*)(colsum + (size_t)n * L_ + kg);
    *(float4*)&cv[4] = *(const float4*)(colsum + (size_t)n * L_ + kg + 4);
    u16* u = (u16*)&v;
#pragma unroll
    for (int s = 0; s < 8; s++) u[s] = f2bf(bf2f(u[s]) / cv[s]);
    *(uint4*)p = v;
}

// ---------------------------------------------------------------
// K4: att[n,q,d] = sum_k e[q,k] * vt'[d,k]  (both row-major in k).
// Round-0 proven geometry: grid (4 q-tiles, 128 n), 4 waves (2x2),
// wave tile 64q x 64d (acc[4][4]).  att aliases qb.
// ---------------------------------------------------------------
__global__ __launch_bounds__(256) void k4_av(
    const u16* __restrict__ sb, const u16* __restrict__ vtb,
    u16* __restrict__ att) {
    const int q0 = blockIdx.x * 128;
    const int n  = blockIdx.y;
    const int lane = threadIdx.x & 63, wave = threadIdx.x >> 6;
    const int wr = wave >> 1, wc = wave & 1;
    const int mr = lane & 15, quad = lane >> 4;

    f32x4 acc[4][4];
#pragma unroll
    for (int i = 0; i < 4; i++)
#pragma unroll
        for (int j = 0; j < 4; j++) acc[i][j] = (f32x4){0.f, 0.f, 0.f, 0.f};

    mfma_bt64(sb + ((size_t)n * L_ + q0 + wr * 64) * L_, L_,
              vtb + ((size_t)n * D_ + wc * 64) * L_, L_, L_, lane, acc);

    __shared__ __align__(16) u16 T[128][136];
#pragma unroll
    for (int i = 0; i < 4; i++)
#pragma unroll
        for (int j = 0; j < 4; j++) {
            int col = wc * 64 + j * 16 + mr;
#pragma unroll
            for (int r = 0; r < 4; r++)
                T[wr * 64 + i * 16 + quad * 4 + r][col] = f2bf(acc[i][j][r]);
        }
    __syncthreads();
    int t = threadIdx.x, row = t >> 1, c0 = (t & 1) * 64;
    u16* dst = att + ((size_t)n * L_ + q0 + row) * D_ + c0;
#pragma unroll
    for (int c = 0; c < 64; c += 8)
        *(uint4*)(dst + c) = *(const uint4*)&T[row][c0 + c];
}

// ---------------------------------------------------------------
// K5: out = att_flat[8192][1024] @ Wo[128][1024]^T + bo.
// BM=32, BN=128, 4 waves (wave w: 32q x 32 cols, acc[2][2]),
// grid 256 -> one block per CU (was 128 blocks x 2 waves = 3% occ).
// ---------------------------------------------------------------
__global__ __launch_bounds__(256) void k5_out(
    const u16* __restrict__ att, const u16* __restrict__ Wob,
    const u16* __restrict__ bob, const int* __restrict__ flags,
    void* __restrict__ out) {
    const int dt = flags[0];
    const int m0 = blockIdx.x * 32;
    const int lane = threadIdx.x & 63, wave = threadIdx.x >> 6;
    const int mr = lane & 15, quad = lane >> 4;

    f32x4 acc[2][2];
#pragma unroll
    for (int i = 0; i < 2; i++)
#pragma unroll
        for (int j = 0; j < 2; j++) acc[i][j] = (f32x4){0.f, 0.f, 0.f, 0.f};

    const u16* A  = att + (size_t)m0 * HD_;
    const u16* Bw = Wob + (size_t)(wave * 32) * HD_;
    for (int k0 = 0; k0 < HD_; k0 += 32) {
        s16x8 av[2], bv[2];
#pragma unroll
        for (int i = 0; i < 2; i++)
            av[i] = *(const s16x8*)(A + (size_t)(i * 16 + mr) * HD_ + k0 + quad * 8);
#pragma unroll
        for (int j = 0; j < 2; j++)
            bv[j] = *(const s16x8*)(Bw + (size_t)(j * 16 + mr) * HD_ + k0 + quad * 8);
#pragma unroll
        for (int i = 0; i < 2; i++)
#pragma unroll
            for (int j = 0; j < 2; j++)
                acc[i][j] = __builtin_amdgcn_mfma_f32_16x16x32_bf16(av[i], bv[j], acc[i][j], 0, 0, 0);
    }

    __shared__ __align__(16) float Tf[32][132];
#pragma unroll
    for (int i = 0; i < 2; i++)
#pragma unroll
        for (int j = 0; j < 2; j++) {
            int col = wave * 32 + j * 16 + mr;
            float bv_ = bf2f(bob[col]);
#pragma unroll
            for (int r = 0; r < 4; r++)
                Tf[i * 16 + quad * 4 + r][col] = acc[i][j][r] + bv_;
        }
    __syncthreads();
    int t = threadIdx.x, row = t >> 3, cg = (t & 7) * 16;
    size_t base = (size_t)(m0 + row) * D_ + cg;
    if (dt) {
        u16* o = (u16*)out;
        u16 tmp[16];
#pragma unroll
        for (int s = 0; s < 16; s++) tmp[s] = f2bf(Tf[row][cg + s]);
        *(uint4*)(o + base)     = *(const uint4*)&tmp[0];
        *(uint4*)(o + base + 8) = *(const uint4*)&tmp[8];
    } else {
        float* o = (float*)out;
#pragma unroll
        for (int c = 0; c < 16; c += 4)
            *(float4*)(o + base + c) = *(const float4*)&Tf[row][cg + c];
    }
}

// ---------------------------------------------------------------
extern "C" void kernel_launch(void* const* d_in, const int* in_sizes, int n_in,
                              void* d_out, int out_size, void* d_ws, size_t ws_size,
                              hipStream_t stream) {
    (void)in_sizes; (void)n_in; (void)out_size; (void)ws_size;
    const void* x  = d_in[0];
    const void* Wq = d_in[1]; const void* bq = d_in[2];
    const void* Wk = d_in[3]; const void* bk = d_in[4];
    const void* Wv = d_in[5]; const void* bv = d_in[6];
    const void* Wo = d_in[7]; const void* bo = d_in[8];
    const void* pad = d_in[9];

    char* p = (char*)d_ws;
    auto alloc = [&](size_t bytes) { char* r = p; p += (bytes + 255) & ~(size_t)255; return r; };
    int*  flags = (int*)alloc(256);
    u16*  xb   = (u16*)alloc(2097152);
    u16*  Wqb  = (u16*)alloc(262144);
    u16*  Wkb  = (u16*)alloc(262144);
    u16*  Wvb  = (u16*)alloc(262144);
    u16*  Wob  = (u16*)alloc(262144);
    u16*  bqb  = (u16*)alloc(2048);
    u16*  bkb  = (u16*)alloc(2048);
    u16*  bvb  = (u16*)alloc(2048);
    u16*  bob  = (u16*)alloc(256);
    unsigned* mbits = (unsigned*)alloc(524288);
    float* colsum = (float*)alloc(262144);    // [128 n][512 k] fp32
    u16*  qb   = (u16*)alloc(16777216);
    u16*  kb   = (u16*)alloc(16777216);
    u16*  vtb  = (u16*)alloc(16777216);
    u16*  sb   = (u16*)alloc(67108864);
    u16*  att  = qb;   // alias: qb dead after k2; k4 writes disjoint q-rows

    k0_detect<<<1, 256, 0, stream>>>((const unsigned*)pad, (const unsigned*)x, flags);
    kprep_conv<<<(PREP_TOT + 255) / 256, 256, 0, stream>>>(
        x, Wq, bq, Wk, bk, Wv, bv, Wo, bo, flags,
        xb, Wqb, Wkb, Wvb, Wob, bqb, bkb, bvb, bob);
    kprep_mask<<<512, 256, 0, stream>>>(pad, flags, mbits, colsum);
    k1_proj<<<dim3(8, 64, 3), 256, 0, stream>>>(
        xb, Wqb, Wkb, Wvb, bqb, bkb, bvb, qb, kb, vtb);
    k2_scores<<<dim3(16, NH_), 256, 0, stream>>>(qb, kb, mbits, sb, colsum);
    k3_vscale<<<4096, 256, 0, stream>>>(vtb, colsum);
    k4_av<<<dim3(4, NH_), 256, 0, stream>>>(sb, vtb, att);
    k5_out<<<256, 256, 0, stream>>>(att, Wob, bob, flags, d_out);
}

// Round 4
// 244.890 us; speedup vs baseline: 1.2095x; 1.0348x over previous
//
#include <hip/hip_runtime.h>

// Problem constants (B, L, D, H) = (16, 512, 128, 8)
#define B_  16
#define L_  512
#define D_  128
#define H_  8
#define HD_ 1024   // H*D
#define NH_ 128    // H*B
#define M_  8192   // B*L

typedef unsigned short u16;
typedef __attribute__((ext_vector_type(8))) short s16x8;   // 8 bf16 = 4 VGPRs
typedef __attribute__((ext_vector_type(4))) float f32x4;   // MFMA accumulator

// ---------- bf16 helpers (raw ushort representation) ----------
__device__ __forceinline__ float bf2f(u16 u) {
    union { unsigned u; float f; } x; x.u = ((unsigned)u) << 16; return x.f;
}
__device__ __forceinline__ u16 f2bf(float f) {
    unsigned u = __float_as_uint(f);
    return (u16)((u + 0x7FFFu + ((u >> 16) & 1u)) >> 16);   // RNE
}

// ---------------------------------------------------------------
// MFMA bt-core: C(64x64) = A(64xK) @ B(64xK)^T for one wave.
// Fragment layout (m89/m120-verified):
//   A/B operand: row = lane&15, k = (lane>>4)*8 + j  (16B contiguous)
//   C/D:         col = lane&15, row = (lane>>4)*4 + reg
// ---------------------------------------------------------------
__device__ __forceinline__ void mfma_bt64(const u16* __restrict__ A, int lda,
                                          const u16* __restrict__ B, int ldb,
                                          int K, int lane, f32x4 acc[4][4]) {
    const int mr = lane & 15, quad = lane >> 4;
    for (int k0 = 0; k0 < K; k0 += 32) {
        s16x8 av[4], bv[4];
#pragma unroll
        for (int i = 0; i < 4; i++)
            av[i] = *(const s16x8*)(A + (size_t)(i * 16 + mr) * lda + k0 + quad * 8);
#pragma unroll
        for (int j = 0; j < 4; j++)
            bv[j] = *(const s16x8*)(B + (size_t)(j * 16 + mr) * ldb + k0 + quad * 8);
#pragma unroll
        for (int i = 0; i < 4; i++)
#pragma unroll
            for (int j = 0; j < 4; j++)
                acc[i][j] = __builtin_amdgcn_mfma_f32_16x16x32_bf16(av[i], bv[j], acc[i][j], 0, 0, 0);
    }
}

// ---------------------------------------------------------------
// K0: detect float dtype (fp32 vs packed bf16) + mask dtype (i32 vs u8).
// ---------------------------------------------------------------
__global__ void k0_detect(const unsigned int* __restrict__ pad,
                          const unsigned int* __restrict__ xw,
                          int* __restrict__ flags) {
    __shared__ int sMask, sCnt;
    if (threadIdx.x == 0) { sMask = 0; sCnt = 0; }
    __syncthreads();
    int bad = 0;
#pragma unroll
    for (int i = 0; i < 4; i++) {
        unsigned u = pad[threadIdx.x * 4 + i];
        bad |= (u > 1u) ? 1 : 0;
    }
    int cnt = 0;
#pragma unroll
    for (int i = 0; i < 16; i++) {
        unsigned w = xw[threadIdx.x * 16 + i];
        unsigned e = (w >> 7) & 0xFFu;
        cnt += (e >= 100u && e <= 131u) ? 1 : 0;
    }
    if (bad) atomicOr(&sMask, 1);
    atomicAdd(&sCnt, cnt);
    __syncthreads();
    if (threadIdx.x == 0) {
        flags[0] = (sCnt > 2048) ? 1 : 0;   // 1 => floats are bf16
        flags[1] = sMask;                   // 1 => mask is uint8
    }
}

// ---------------------------------------------------------------
// Kprep_conv: normalize all float inputs to bf16 in ws, 8 elems/thread
// (uint4-vectorized both paths; all segment boundaries are %8==0).
// ---------------------------------------------------------------
#define PREP_TOT 1576064
#define PREP_V   197008   // PREP_TOT / 8
__global__ __launch_bounds__(256) void kprep_conv(
    const void* x, const void* Wq, const void* bq, const void* Wk, const void* bk,
    const void* Wv, const void* bv, const void* Wo, const void* bo,
    const int* __restrict__ flags,
    u16* xb, u16* Wqb, u16* Wkb, u16* Wvb, u16* Wob,
    u16* bqb, u16* bkb, u16* bvb, u16* bob) {
    int gid = blockIdx.x * 256 + threadIdx.x;
    if (gid >= PREP_V) return;
    int e0 = gid * 8;
    const int dt = flags[0];
    const void* src; u16* dst; int off;
    if      (e0 < 1048576) { src = x;  dst = xb;  off = e0; }
    else if (e0 < 1179648) { src = Wq; dst = Wqb; off = e0 - 1048576; }
    else if (e0 < 1310720) { src = Wk; dst = Wkb; off = e0 - 1179648; }
    else if (e0 < 1441792) { src = Wv; dst = Wvb; off = e0 - 1310720; }
    else if (e0 < 1572864) { src = Wo; dst = Wob; off = e0 - 1441792; }
    else if (e0 < 1573888) { src = bq; dst = bqb; off = e0 - 1572864; }
    else if (e0 < 1574912) { src = bk; dst = bkb; off = e0 - 1573888; }
    else if (e0 < 1575936) { src = bv; dst = bvb; off = e0 - 1574912; }
    else                   { src = bo; dst = bob; off = e0 - 1575936; }
    if (dt) {
        *(uint4*)(dst + off) = *(const uint4*)((const u16*)src + off);
    } else {
        const float* s = (const float*)src + off;
        float4 a = *(const float4*)s, b = *(const float4*)(s + 4);
        u16 tmp[8] = {f2bf(a.x), f2bf(a.y), f2bf(a.z), f2bf(a.w),
                      f2bf(b.x), f2bf(b.y), f2bf(b.z), f2bf(b.w)};
        *(uint4*)(dst + off) = *(const uint4*)tmp;
    }
}

// ---------------------------------------------------------------
// Kprep_mask: pack pad_mask into bitmask [16][512][16 u32 words].
// Vectorized (uint4) loads; also zeroes colsum for k2_scores.
// ---------------------------------------------------------------
__global__ __launch_bounds__(256) void kprep_mask(const void* __restrict__ pad,
                                                  const int* __restrict__ flags,
                                                  unsigned* __restrict__ mb,
                                                  float* __restrict__ colsum) {
    int w = blockIdx.x * 256 + threadIdx.x;     // < 131072
    if (w < NH_ * L_) colsum[w] = 0.0f;         // 65536 floats
    unsigned m = 0;
    if (flags[1]) {                              // uint8 mask: 32 B = 2 uint4
        const uint4* p = (const uint4*)pad + (size_t)w * 2;
        uint4 a = p[0], b = p[1];
        unsigned ws[8] = {a.x, a.y, a.z, a.w, b.x, b.y, b.z, b.w};
#pragma unroll
        for (int i = 0; i < 8; i++) {
            unsigned v = ws[i];
            m |= ((v & 0xFFu)        ? 1u : 0u) << (i * 4)
               | ((v & 0xFF00u)     ? 1u : 0u) << (i * 4 + 1)
               | ((v & 0xFF0000u)   ? 1u : 0u) << (i * 4 + 2)
               | ((v & 0xFF000000u) ? 1u : 0u) << (i * 4 + 3);
        }
    } else {                                     // int32 mask: 128 B = 8 uint4
        const uint4* p = (const uint4*)pad + (size_t)w * 8;
#pragma unroll
        for (int i = 0; i < 8; i++) {
            uint4 v = p[i];
            m |= (v.x ? 1u : 0u) << (i * 4)
               | (v.y ? 1u : 0u) << (i * 4 + 1)
               | (v.z ? 1u : 0u) << (i * 4 + 2)
               | (v.w ? 1u : 0u) << (i * 4 + 3);
        }
    }
    mb[w] = m;
}

// ---------------------------------------------------------------
// K1: QKV projection via MFMA.  y = x @ W^T + b.
// q,k written head-major [n=h*16+bb][l][d]; v written TRANSPOSED [n][d][l].
// grid (64 m-tiles, 8 heads, 3): m-tile on x so the 8 head-blocks that
// share one x-tile are stride-64 in linear id == same XCD (L2 reuse).
// ---------------------------------------------------------------
__global__ __launch_bounds__(256) void k1_proj(
    const u16* __restrict__ xb,
    const u16* __restrict__ Wqb, const u16* __restrict__ Wkb, const u16* __restrict__ Wvb,
    const u16* __restrict__ bqb, const u16* __restrict__ bkb, const u16* __restrict__ bvb,
    u16* __restrict__ qb, u16* __restrict__ kb, u16* __restrict__ vtb) {
    const int h  = blockIdx.y;           // e-tile == head (128 e per head)
    const int m0 = blockIdx.x * 128;
    const int z  = blockIdx.z;
    const u16* W    = (z == 0) ? Wqb : (z == 1) ? Wkb : Wvb;
    const u16* bias = (z == 0) ? bqb : (z == 1) ? bkb : bvb;

    const int lane = threadIdx.x & 63, wave = threadIdx.x >> 6;
    const int wr = wave >> 1, wc = wave & 1;
    const int mr = lane & 15, quad = lane >> 4;

    f32x4 acc[4][4];
#pragma unroll
    for (int i = 0; i < 4; i++)
#pragma unroll
        for (int j = 0; j < 4; j++) acc[i][j] = (f32x4){0.f, 0.f, 0.f, 0.f};

    mfma_bt64(xb + (size_t)(m0 + wr * 64) * D_, D_,
              W + (size_t)(h * 128 + wc * 64) * D_, D_, D_, lane, acc);

    __shared__ __align__(16) u16 T[128][144];
#pragma unroll
    for (int i = 0; i < 4; i++)
#pragma unroll
        for (int j = 0; j < 4; j++) {
            int col = wc * 64 + j * 16 + mr;
            float bv_ = bf2f(bias[h * 128 + col]);
#pragma unroll
            for (int r = 0; r < 4; r++)
                T[wr * 64 + i * 16 + quad * 4 + r][col] = f2bf(acc[i][j][r] + bv_);
        }
    __syncthreads();

    const int bb = m0 >> 9, l0 = m0 & 511;
    const int t = threadIdx.x;
    if (z < 2) {
        u16* out = z ? kb : qb;
        int row = t >> 1, c0 = (t & 1) * 64;
        u16* dst = out + ((size_t)(h * B_ + bb) * L_ + l0 + row) * D_ + c0;
#pragma unroll
        for (int c = 0; c < 64; c += 8)
            *(uint4*)(dst + c) = *(const uint4*)&T[row][c0 + c];
    } else {
        int d = t >> 1, lc0 = (t & 1) * 64;
        u16* dst = vtb + ((size_t)(h * B_ + bb) * D_ + d) * L_ + l0 + lc0;
#pragma unroll
        for (int c = 0; c < 64; c += 8) {
            u16 tmp[8];
#pragma unroll
            for (int s = 0; s < 8; s++) tmp[s] = T[lc0 + c + s][d];
            *(uint4*)(dst + c) = *(const uint4*)tmp;
        }
    }
}

// ---------------------------------------------------------------
// K2: e-tile (128q x 128k) per block + pre-reduced colsum atomics.
// grid (16 = qt*4+kt, 128 n), 256 threads, 4 waves (2x2).
// ---------------------------------------------------------------
__global__ __launch_bounds__(256, 4) void k2_scores(
    const u16* __restrict__ qb, const u16* __restrict__ kb,
    const unsigned* __restrict__ mbits,
    u16* __restrict__ sb, float* __restrict__ colsum) {
    const int qt = blockIdx.x >> 2, kt = blockIdx.x & 3;
    const int n  = blockIdx.y;
    const int bb = n & (B_ - 1);
    const int lane = threadIdx.x & 63, wave = threadIdx.x >> 6;
    const int wr = wave >> 1, wc = wave & 1;
    const int mr = lane & 15, quad = lane >> 4;
    const float rs = 0.08838834764831845f;   // 1/sqrt(128)

    __shared__ __align__(16) u16 T[128][136];
    __shared__ float CS[2][128];
    __shared__ unsigned MW[128][4];

    // stage this block's mask words: 128 q-rows x 4 dwords (2KB)
    {
        int t = threadIdx.x;
        int q = t >> 1, w2 = (t & 1) * 2;
        const unsigned* src = mbits + ((size_t)(bb << 9) + qt * 128 + q) * 16 + kt * 4 + w2;
        uint2 v = *(const uint2*)src;
        MW[q][w2] = v.x; MW[q][w2 + 1] = v.y;
    }

    f32x4 acc[4][4];
#pragma unroll
    for (int i = 0; i < 4; i++)
#pragma unroll
        for (int j = 0; j < 4; j++) acc[i][j] = (f32x4){0.f, 0.f, 0.f, 0.f};

    mfma_bt64(qb + ((size_t)n * L_ + qt * 128 + wr * 64) * D_, D_,
              kb + ((size_t)n * L_ + kt * 128 + wc * 64) * D_, D_, D_, lane, acc);
    __syncthreads();   // MW visible (latency hidden under MFMA)

    float cs[4] = {0.f, 0.f, 0.f, 0.f};
#pragma unroll
    for (int j = 0; j < 4; j++) {
        const int wsel = wc * 2 + (j >> 1);
        const int bit  = ((j & 1) << 4) + mr;
#pragma unroll
        for (int i = 0; i < 4; i++)
#pragma unroll
            for (int r = 0; r < 4; r++) {
                int ql = wr * 64 + i * 16 + quad * 4 + r;
                unsigned w = MW[ql][wsel];
                float e = ((w >> bit) & 1u) ? 0.f : __expf(acc[i][j][r] * rs);
                cs[j] += e;
                T[ql][wc * 64 + j * 16 + mr] = f2bf(e);
            }
    }
    // reduce over the 4 quads (same column within the wave)
#pragma unroll
    for (int j = 0; j < 4; j++) {
        cs[j] += __shfl_xor(cs[j], 16);
        cs[j] += __shfl_xor(cs[j], 32);
    }
    if (quad == 0) {
#pragma unroll
        for (int j = 0; j < 4; j++) CS[wr][wc * 64 + j * 16 + mr] = cs[j];
    }
    __syncthreads();
    // coalesced e-store
    {
        int t = threadIdx.x, row = t >> 1, c0 = (t & 1) * 64;
        u16* dst = sb + ((size_t)n * L_ + qt * 128 + row) * L_ + kt * 128 + c0;
#pragma unroll
        for (int c = 0; c < 64; c += 8)
            *(uint4*)(dst + c) = *(const uint4*)&T[row][c0 + c];
    }
    // one atomic per column per block (4 blocks contribute per column)
    if (threadIdx.x < 128)
        atomicAdd(&colsum[(size_t)n * L_ + kt * 128 + threadIdx.x],
                  CS[0][threadIdx.x] + CS[1][threadIdx.x]);
}

// ---------------------------------------------------------------
// K4: att[n,q,d] = sum_k (e[q,k]/colsum[k]) * vt'[d,k].
// The 1/colsum scale is folded into the A-fragment load (replaces the
// old k3 v-scale pass: -66MB RMW, -1 launch).  Round-0 geometry:
// grid (4 q-tiles, 128 n), 4 waves (2x2), wave tile 64q x 64d.
// ---------------------------------------------------------------
__global__ __launch_bounds__(256) void k4_av(
    const u16* __restrict__ sb, const u16* __restrict__ vtb,
    const float* __restrict__ colsum, u16* __restrict__ att) {
    const int q0 = blockIdx.x * 128;
    const int n  = blockIdx.y;
    const int lane = threadIdx.x & 63, wave = threadIdx.x >> 6;
    const int wr = wave >> 1, wc = wave & 1;
    const int mr = lane & 15, quad = lane >> 4;

    f32x4 acc[4][4];
#pragma unroll
    for (int i = 0; i < 4; i++)
#pragma unroll
        for (int j = 0; j < 4; j++) acc[i][j] = (f32x4){0.f, 0.f, 0.f, 0.f};

    const u16* A   = sb  + ((size_t)n * L_ + q0 + wr * 64) * L_;
    const u16* Bb  = vtb + ((size_t)n * D_ + wc * 64) * L_;
    const float* cs = colsum + (size_t)n * L_;

    for (int k0 = 0; k0 < L_; k0 += 32) {
        const int kk = k0 + quad * 8;
        float lv[8];
        *(float4*)&lv[0] = *(const float4*)(cs + kk);
        *(float4*)&lv[4] = *(const float4*)(cs + kk + 4);
#pragma unroll
        for (int s = 0; s < 8; s++) lv[s] = __builtin_amdgcn_rcpf(lv[s]);

        s16x8 av[4], bv[4];
#pragma unroll
        for (int i = 0; i < 4; i++)
            av[i] = *(const s16x8*)(A + (size_t)(i * 16 + mr) * L_ + kk);
#pragma unroll
        for (int j = 0; j < 4; j++)
            bv[j] = *(const s16x8*)(Bb + (size_t)(j * 16 + mr) * L_ + kk);
        // scale e by 1/colsum[k] (per-k, pre-MFMA)
#pragma unroll
        for (int i = 0; i < 4; i++) {
            u16* u = (u16*)&av[i];
#pragma unroll
            for (int s = 0; s < 8; s++) u[s] = f2bf(bf2f(u[s]) * lv[s]);
        }
#pragma unroll
        for (int i = 0; i < 4; i++)
#pragma unroll
            for (int j = 0; j < 4; j++)
                acc[i][j] = __builtin_amdgcn_mfma_f32_16x16x32_bf16(av[i], bv[j], acc[i][j], 0, 0, 0);
    }

    __shared__ __align__(16) u16 T[128][136];
#pragma unroll
    for (int i = 0; i < 4; i++)
#pragma unroll
        for (int j = 0; j < 4; j++) {
            int col = wc * 64 + j * 16 + mr;
#pragma unroll
            for (int r = 0; r < 4; r++)
                T[wr * 64 + i * 16 + quad * 4 + r][col] = f2bf(acc[i][j][r]);
        }
    __syncthreads();
    int t = threadIdx.x, row = t >> 1, c0 = (t & 1) * 64;
    u16* dst = att + ((size_t)n * L_ + q0 + row) * D_ + c0;
#pragma unroll
    for (int c = 0; c < 64; c += 8)
        *(uint4*)(dst + c) = *(const uint4*)&T[row][c0 + c];
}

// ---------------------------------------------------------------
// K5: out = att_flat[8192][1024] @ Wo[128][1024]^T + bo.
// BM=32, BN=128, 4 waves (wave w: 32q x 32 cols, acc[2][2]), grid 256.
// ---------------------------------------------------------------
__global__ __launch_bounds__(256) void k5_out(
    const u16* __restrict__ att, const u16* __restrict__ Wob,
    const u16* __restrict__ bob, const int* __restrict__ flags,
    void* __restrict__ out) {
    const int dt = flags[0];
    const int m0 = blockIdx.x * 32;
    const int lane = threadIdx.x & 63, wave = threadIdx.x >> 6;
    const int mr = lane & 15, quad = lane >> 4;

    f32x4 acc[2][2];
#pragma unroll
    for (int i = 0; i < 2; i++)
#pragma unroll
        for (int j = 0; j < 2; j++) acc[i][j] = (f32x4){0.f, 0.f, 0.f, 0.f};

    const u16* A  = att + (size_t)m0 * HD_;
    const u16* Bw = Wob + (size_t)(wave * 32) * HD_;
    for (int k0 = 0; k0 < HD_; k0 += 32) {
        s16x8 av[2], bv[2];
#pragma unroll
        for (int i = 0; i < 2; i++)
            av[i] = *(const s16x8*)(A + (size_t)(i * 16 + mr) * HD_ + k0 + quad * 8);
#pragma unroll
        for (int j = 0; j < 2; j++)
            bv[j] = *(const s16x8*)(Bw + (size_t)(j * 16 + mr) * HD_ + k0 + quad * 8);
#pragma unroll
        for (int i = 0; i < 2; i++)
#pragma unroll
            for (int j = 0; j < 2; j++)
                acc[i][j] = __builtin_amdgcn_mfma_f32_16x16x32_bf16(av[i], bv[j], acc[i][j], 0, 0, 0);
    }

    __shared__ __align__(16) float Tf[32][132];
#pragma unroll
    for (int i = 0; i < 2; i++)
#pragma unroll
        for (int j = 0; j < 2; j++) {
            int col = wave * 32 + j * 16 + mr;
            float bv_ = bf2f(bob[col]);
#pragma unroll
            for (int r = 0; r < 4; r++)
                Tf[i * 16 + quad * 4 + r][col] = acc[i][j][r] + bv_;
        }
    __syncthreads();
    int t = threadIdx.x, row = t >> 3, cg = (t & 7) * 16;
    size_t base = (size_t)(m0 + row) * D_ + cg;
    if (dt) {
        u16* o = (u16*)out;
        u16 tmp[16];
#pragma unroll
        for (int s = 0; s < 16; s++) tmp[s] = f2bf(Tf[row][cg + s]);
        *(uint4*)(o + base)     = *(const uint4*)&tmp[0];
        *(uint4*)(o + base + 8) = *(const uint4*)&tmp[8];
    } else {
        float* o = (float*)out;
#pragma unroll
        for (int c = 0; c < 16; c += 4)
            *(float4*)(o + base + c) = *(const float4*)&Tf[row][cg + c];
    }
}

// ---------------------------------------------------------------
extern "C" void kernel_launch(void* const* d_in, const int* in_sizes, int n_in,
                              void* d_out, int out_size, void* d_ws, size_t ws_size,
                              hipStream_t stream) {
    (void)in_sizes; (void)n_in; (void)out_size; (void)ws_size;
    const void* x  = d_in[0];
    const void* Wq = d_in[1]; const void* bq = d_in[2];
    const void* Wk = d_in[3]; const void* bk = d_in[4];
    const void* Wv = d_in[5]; const void* bv = d_in[6];
    const void* Wo = d_in[7]; const void* bo = d_in[8];
    const void* pad = d_in[9];

    char* p = (char*)d_ws;
    auto alloc = [&](size_t bytes) { char* r = p; p += (bytes + 255) & ~(size_t)255; return r; };
    int*  flags = (int*)alloc(256);
    u16*  xb   = (u16*)alloc(2097152);
    u16*  Wqb  = (u16*)alloc(262144);
    u16*  Wkb  = (u16*)alloc(262144);
    u16*  Wvb  = (u16*)alloc(262144);
    u16*  Wob  = (u16*)alloc(262144);
    u16*  bqb  = (u16*)alloc(2048);
    u16*  bkb  = (u16*)alloc(2048);
    u16*  bvb  = (u16*)alloc(2048);
    u16*  bob  = (u16*)alloc(256);
    unsigned* mbits = (unsigned*)alloc(524288);
    float* colsum = (float*)alloc(262144);    // [128 n][512 k] fp32
    u16*  qb   = (u16*)alloc(16777216);
    u16*  kb   = (u16*)alloc(16777216);
    u16*  vtb  = (u16*)alloc(16777216);
    u16*  sb   = (u16*)alloc(67108864);
    u16*  att  = qb;   // alias: qb dead after k2; k4 writes disjoint q-rows

    k0_detect<<<1, 256, 0, stream>>>((const unsigned*)pad, (const unsigned*)x, flags);
    kprep_conv<<<(PREP_V + 255) / 256, 256, 0, stream>>>(
        x, Wq, bq, Wk, bk, Wv, bv, Wo, bo, flags,
        xb, Wqb, Wkb, Wvb, Wob, bqb, bkb, bvb, bob);
    kprep_mask<<<512, 256, 0, stream>>>(pad, flags, mbits, colsum);
    k1_proj<<<dim3(64, 8, 3), 256, 0, stream>>>(
        xb, Wqb, Wkb, Wvb, bqb, bkb, bvb, qb, kb, vtb);
    k2_scores<<<dim3(16, NH_), 256, 0, stream>>>(qb, kb, mbits, sb, colsum);
    k4_av<<<dim3(4, NH_), 256, 0, stream>>>(sb, vtb, colsum, att);
    k5_out<<<256, 256, 0, stream>>>(att, Wob, bob, flags, d_out);
}

// Round 5
// 228.492 us; speedup vs baseline: 1.2963x; 1.0718x over previous
//
#include <hip/hip_runtime.h>

// Problem constants (B, L, D, H) = (16, 512, 128, 8)
#define B_  16
#define L_  512
#define D_  128
#define H_  8
#define HD_ 1024   // H*D
#define NH_ 128    // H*B
#define M_  8192   // B*L

typedef unsigned short u16;
typedef __attribute__((ext_vector_type(8))) short s16x8;   // 8 bf16 = 4 VGPRs
typedef __attribute__((ext_vector_type(4))) float f32x4;   // MFMA accumulator

// ---------- bf16 helpers (raw ushort representation) ----------
__device__ __forceinline__ float bf2f(u16 u) {
    union { unsigned u; float f; } x; x.u = ((unsigned)u) << 16; return x.f;
}
__device__ __forceinline__ u16 f2bf(float f) {
    unsigned u = __float_as_uint(f);
    return (u16)((u + 0x7FFFu + ((u >> 16) & 1u)) >> 16);   // RNE
}

// ---------------------------------------------------------------
// MFMA bt-core: C(64x64) = A(64xK) @ B(64xK)^T for one wave.
// Fragment layout (m89/m120-verified):
//   A/B operand: row = lane&15, k = (lane>>4)*8 + j  (16B contiguous)
//   C/D:         col = lane&15, row = (lane>>4)*4 + reg
// ---------------------------------------------------------------
__device__ __forceinline__ void mfma_bt64(const u16* __restrict__ A, int lda,
                                          const u16* __restrict__ B, int ldb,
                                          int K, int lane, f32x4 acc[4][4]) {
    const int mr = lane & 15, quad = lane >> 4;
    for (int k0 = 0; k0 < K; k0 += 32) {
        s16x8 av[4], bv[4];
#pragma unroll
        for (int i = 0; i < 4; i++)
            av[i] = *(const s16x8*)(A + (size_t)(i * 16 + mr) * lda + k0 + quad * 8);
#pragma unroll
        for (int j = 0; j < 4; j++)
            bv[j] = *(const s16x8*)(B + (size_t)(j * 16 + mr) * ldb + k0 + quad * 8);
#pragma unroll
        for (int i = 0; i < 4; i++)
#pragma unroll
            for (int j = 0; j < 4; j++)
                acc[i][j] = __builtin_amdgcn_mfma_f32_16x16x32_bf16(av[i], bv[j], acc[i][j], 0, 0, 0);
    }
}

// ---------------------------------------------------------------
// K0: detect float dtype (fp32 vs packed bf16) + mask dtype (i32 vs u8).
// ---------------------------------------------------------------
__global__ void k0_detect(const unsigned int* __restrict__ pad,
                          const unsigned int* __restrict__ xw,
                          int* __restrict__ flags) {
    __shared__ int sMask, sCnt;
    if (threadIdx.x == 0) { sMask = 0; sCnt = 0; }
    __syncthreads();
    int bad = 0;
#pragma unroll
    for (int i = 0; i < 4; i++) {
        unsigned u = pad[threadIdx.x * 4 + i];
        bad |= (u > 1u) ? 1 : 0;
    }
    int cnt = 0;
#pragma unroll
    for (int i = 0; i < 16; i++) {
        unsigned w = xw[threadIdx.x * 16 + i];
        unsigned e = (w >> 7) & 0xFFu;
        cnt += (e >= 100u && e <= 131u) ? 1 : 0;
    }
    if (bad) atomicOr(&sMask, 1);
    atomicAdd(&sCnt, cnt);
    __syncthreads();
    if (threadIdx.x == 0) {
        flags[0] = (sCnt > 2048) ? 1 : 0;   // 1 => floats are bf16
        flags[1] = sMask;                   // 1 => mask is uint8
    }
}

// ---------------------------------------------------------------
// Kprep_conv: normalize all float inputs to bf16 in ws, 8 elems/thread
// (uint4-vectorized both paths; all segment boundaries are %8==0).
// ---------------------------------------------------------------
#define PREP_TOT 1576064
#define PREP_V   197008   // PREP_TOT / 8
__global__ __launch_bounds__(256) void kprep_conv(
    const void* x, const void* Wq, const void* bq, const void* Wk, const void* bk,
    const void* Wv, const void* bv, const void* Wo, const void* bo,
    const int* __restrict__ flags,
    u16* xb, u16* Wqb, u16* Wkb, u16* Wvb, u16* Wob,
    u16* bqb, u16* bkb, u16* bvb, u16* bob) {
    int gid = blockIdx.x * 256 + threadIdx.x;
    if (gid >= PREP_V) return;
    int e0 = gid * 8;
    const int dt = flags[0];
    const void* src; u16* dst; int off;
    if      (e0 < 1048576) { src = x;  dst = xb;  off = e0; }
    else if (e0 < 1179648) { src = Wq; dst = Wqb; off = e0 - 1048576; }
    else if (e0 < 1310720) { src = Wk; dst = Wkb; off = e0 - 1179648; }
    else if (e0 < 1441792) { src = Wv; dst = Wvb; off = e0 - 1310720; }
    else if (e0 < 1572864) { src = Wo; dst = Wob; off = e0 - 1441792; }
    else if (e0 < 1573888) { src = bq; dst = bqb; off = e0 - 1572864; }
    else if (e0 < 1574912) { src = bk; dst = bkb; off = e0 - 1573888; }
    else if (e0 < 1575936) { src = bv; dst = bvb; off = e0 - 1574912; }
    else                   { src = bo; dst = bob; off = e0 - 1575936; }
    if (dt) {
        *(uint4*)(dst + off) = *(const uint4*)((const u16*)src + off);
    } else {
        const float* s = (const float*)src + off;
        float4 a = *(const float4*)s, b = *(const float4*)(s + 4);
        u16 tmp[8] = {f2bf(a.x), f2bf(a.y), f2bf(a.z), f2bf(a.w),
                      f2bf(b.x), f2bf(b.y), f2bf(b.z), f2bf(b.w)};
        *(uint4*)(dst + off) = *(const uint4*)tmp;
    }
}

// ---------------------------------------------------------------
// Kprep_mask: pack pad_mask into bitmask [16][512][16 u32 words].
// Vectorized (uint4) loads; also zeroes colsum for k2_scores.
// ---------------------------------------------------------------
__global__ __launch_bounds__(256) void kprep_mask(const void* __restrict__ pad,
                                                  const int* __restrict__ flags,
                                                  unsigned* __restrict__ mb,
                                                  float* __restrict__ colsum) {
    int w = blockIdx.x * 256 + threadIdx.x;     // < 131072
    if (w < NH_ * L_) colsum[w] = 0.0f;         // 65536 floats
    unsigned m = 0;
    if (flags[1]) {                              // uint8 mask: 32 B = 2 uint4
        const uint4* p = (const uint4*)pad + (size_t)w * 2;
        uint4 a = p[0], b = p[1];
        unsigned ws[8] = {a.x, a.y, a.z, a.w, b.x, b.y, b.z, b.w};
#pragma unroll
        for (int i = 0; i < 8; i++) {
            unsigned v = ws[i];
            m |= ((v & 0xFFu)        ? 1u : 0u) << (i * 4)
               | ((v & 0xFF00u)     ? 1u : 0u) << (i * 4 + 1)
               | ((v & 0xFF0000u)   ? 1u : 0u) << (i * 4 + 2)
               | ((v & 0xFF000000u) ? 1u : 0u) << (i * 4 + 3);
        }
    } else {                                     // int32 mask: 128 B = 8 uint4
        const uint4* p = (const uint4*)pad + (size_t)w * 8;
#pragma unroll
        for (int i = 0; i < 8; i++) {
            uint4 v = p[i];
            m |= (v.x ? 1u : 0u) << (i * 4)
               | (v.y ? 1u : 0u) << (i * 4 + 1)
               | (v.z ? 1u : 0u) << (i * 4 + 2)
               | (v.w ? 1u : 0u) << (i * 4 + 3);
        }
    }
    mb[w] = m;
}

// ---------------------------------------------------------------
// K1: QKV projection via MFMA.  y = x @ W^T + b.
// q,k written head-major [n=h*16+bb][l][d]; v written TRANSPOSED [n][d][l].
// grid (64 m-tiles, 8 heads, 3): m-tile on x so the 8 head-blocks that
// share one x-tile are stride-64 in linear id == same XCD (L2 reuse).
// q/k store: 16 lanes per 256B row, 4 contiguous rows per wave (1KB).
// ---------------------------------------------------------------
__global__ __launch_bounds__(256) void k1_proj(
    const u16* __restrict__ xb,
    const u16* __restrict__ Wqb, const u16* __restrict__ Wkb, const u16* __restrict__ Wvb,
    const u16* __restrict__ bqb, const u16* __restrict__ bkb, const u16* __restrict__ bvb,
    u16* __restrict__ qb, u16* __restrict__ kb, u16* __restrict__ vtb) {
    const int h  = blockIdx.y;           // e-tile == head (128 e per head)
    const int m0 = blockIdx.x * 128;
    const int z  = blockIdx.z;
    const u16* W    = (z == 0) ? Wqb : (z == 1) ? Wkb : Wvb;
    const u16* bias = (z == 0) ? bqb : (z == 1) ? bkb : bvb;

    const int lane = threadIdx.x & 63, wave = threadIdx.x >> 6;
    const int wr = wave >> 1, wc = wave & 1;
    const int mr = lane & 15, quad = lane >> 4;

    f32x4 acc[4][4];
#pragma unroll
    for (int i = 0; i < 4; i++)
#pragma unroll
        for (int j = 0; j < 4; j++) acc[i][j] = (f32x4){0.f, 0.f, 0.f, 0.f};

    mfma_bt64(xb + (size_t)(m0 + wr * 64) * D_, D_,
              W + (size_t)(h * 128 + wc * 64) * D_, D_, D_, lane, acc);

    __shared__ __align__(16) u16 T[128][144];
#pragma unroll
    for (int i = 0; i < 4; i++)
#pragma unroll
        for (int j = 0; j < 4; j++) {
            int col = wc * 64 + j * 16 + mr;
            float bv_ = bf2f(bias[h * 128 + col]);
#pragma unroll
            for (int r = 0; r < 4; r++)
                T[wr * 64 + i * 16 + quad * 4 + r][col] = f2bf(acc[i][j][r] + bv_);
        }
    __syncthreads();

    const int bb = m0 >> 9, l0 = m0 & 511;
    const int t = threadIdx.x;
    if (z < 2) {
        u16* out = z ? kb : qb;
        const int wv = t >> 6, l = t & 63;
        const int col = (l & 15) * 8;
#pragma unroll
        for (int p = 0; p < 8; p++) {
            int row = p * 16 + wv * 4 + (l >> 4);
            u16* dst = out + ((size_t)(h * B_ + bb) * L_ + l0 + row) * D_ + col;
            *(uint4*)dst = *(const uint4*)&T[row][col];
        }
    } else {
        int d = t >> 1, lc0 = (t & 1) * 64;
        u16* dst = vtb + ((size_t)(h * B_ + bb) * D_ + d) * L_ + l0 + lc0;
#pragma unroll
        for (int c = 0; c < 64; c += 8) {
            u16 tmp[8];
#pragma unroll
            for (int s = 0; s < 8; s++) tmp[s] = T[lc0 + c + s][d];
            *(uint4*)(dst + c) = *(const uint4*)tmp;
        }
    }
}

// ---------------------------------------------------------------
// K2: e-tile (128q x 128k) per block + pre-reduced colsum atomics.
// grid (16, 128) XCD-swizzled so XCD x owns n in [16x,16x+16): per-XCD
// q+k working set = 4MB = one L2 (kills cross-XCD re-fetch).
// Store: 16 lanes x 16B = 256B contiguous per row segment.
// ---------------------------------------------------------------
__global__ __launch_bounds__(256, 4) void k2_scores(
    const u16* __restrict__ qb, const u16* __restrict__ kb,
    const unsigned* __restrict__ mbits,
    u16* __restrict__ sb, float* __restrict__ colsum) {
    const int bid = blockIdx.y * 16 + blockIdx.x;       // 0..2047
    const int sw  = (bid & 7) * 256 + (bid >> 3);       // bijective XCD chunking
    const int n   = sw >> 4;
    const int qt  = (sw >> 2) & 3, kt = sw & 3;
    const int bb  = n & (B_ - 1);
    const int lane = threadIdx.x & 63, wave = threadIdx.x >> 6;
    const int wr = wave >> 1, wc = wave & 1;
    const int mr = lane & 15, quad = lane >> 4;
    const float rs = 0.08838834764831845f;   // 1/sqrt(128)

    __shared__ __align__(16) u16 T[128][136];
    __shared__ float CS[2][128];
    __shared__ unsigned MW[128][4];

    // stage this block's mask words: 128 q-rows x 4 dwords (2KB)
    {
        int t = threadIdx.x;
        int q = t >> 1, w2 = (t & 1) * 2;
        const unsigned* src = mbits + ((size_t)(bb << 9) + qt * 128 + q) * 16 + kt * 4 + w2;
        uint2 v = *(const uint2*)src;
        MW[q][w2] = v.x; MW[q][w2 + 1] = v.y;
    }

    f32x4 acc[4][4];
#pragma unroll
    for (int i = 0; i < 4; i++)
#pragma unroll
        for (int j = 0; j < 4; j++) acc[i][j] = (f32x4){0.f, 0.f, 0.f, 0.f};

    mfma_bt64(qb + ((size_t)n * L_ + qt * 128 + wr * 64) * D_, D_,
              kb + ((size_t)n * L_ + kt * 128 + wc * 64) * D_, D_, D_, lane, acc);
    __syncthreads();   // MW visible (latency hidden under MFMA)

    float cs[4] = {0.f, 0.f, 0.f, 0.f};
#pragma unroll
    for (int j = 0; j < 4; j++) {
        const int wsel = wc * 2 + (j >> 1);
        const int bit  = ((j & 1) << 4) + mr;
#pragma unroll
        for (int i = 0; i < 4; i++)
#pragma unroll
            for (int r = 0; r < 4; r++) {
                int ql = wr * 64 + i * 16 + quad * 4 + r;
                unsigned w = MW[ql][wsel];
                float e = ((w >> bit) & 1u) ? 0.f : __expf(acc[i][j][r] * rs);
                cs[j] += e;
                T[ql][wc * 64 + j * 16 + mr] = f2bf(e);
            }
    }
    // reduce over the 4 quads (same column within the wave)
#pragma unroll
    for (int j = 0; j < 4; j++) {
        cs[j] += __shfl_xor(cs[j], 16);
        cs[j] += __shfl_xor(cs[j], 32);
    }
    if (quad == 0) {
#pragma unroll
        for (int j = 0; j < 4; j++) CS[wr][wc * 64 + j * 16 + mr] = cs[j];
    }
    __syncthreads();
    // coalesced e-store: 16 lanes cover one 256B row segment
    {
        int t = threadIdx.x;
        const int col = (t & 15) * 8;
        const int rb  = t >> 4;             // 0..15
#pragma unroll
        for (int p = 0; p < 8; p++) {
            int row = p * 16 + rb;
            u16* dst = sb + ((size_t)n * L_ + qt * 128 + row) * L_ + kt * 128 + col;
            *(uint4*)dst = *(const uint4*)&T[row][col];
        }
    }
    // one atomic per column per block (4 blocks contribute per column)
    if (threadIdx.x < 128)
        atomicAdd(&colsum[(size_t)n * L_ + kt * 128 + threadIdx.x],
                  CS[0][threadIdx.x] + CS[1][threadIdx.x]);
}

// ---------------------------------------------------------------
// K4: att[n,q,d] = sum_k (e[q,k]/colsum[k]) * vt'[d,k].
// 1/colsum folded into the A-fragment load.  grid (4,128) XCD-swizzled
// (XCD x owns n in [16x,16x+16) => vtb fetched once per XCD, not 4x).
// Store: wave writes 1KB contiguous (4 adjacent 256B D-rows).
// ---------------------------------------------------------------
__global__ __launch_bounds__(256) void k4_av(
    const u16* __restrict__ sb, const u16* __restrict__ vtb,
    const float* __restrict__ colsum, u16* __restrict__ att) {
    const int bid = blockIdx.y * 4 + blockIdx.x;        // 0..511
    const int sw  = (bid & 7) * 64 + (bid >> 3);        // bijective XCD chunking
    const int n   = sw >> 2;
    const int q0  = (sw & 3) * 128;
    const int lane = threadIdx.x & 63, wave = threadIdx.x >> 6;
    const int wr = wave >> 1, wc = wave & 1;
    const int mr = lane & 15, quad = lane >> 4;

    f32x4 acc[4][4];
#pragma unroll
    for (int i = 0; i < 4; i++)
#pragma unroll
        for (int j = 0; j < 4; j++) acc[i][j] = (f32x4){0.f, 0.f, 0.f, 0.f};

    const u16* A   = sb  + ((size_t)n * L_ + q0 + wr * 64) * L_;
    const u16* Bb  = vtb + ((size_t)n * D_ + wc * 64) * L_;
    const float* cs = colsum + (size_t)n * L_;

    for (int k0 = 0; k0 < L_; k0 += 32) {
        const int kk = k0 + quad * 8;
        float lv[8];
        *(float4*)&lv[0] = *(const float4*)(cs + kk);
        *(float4*)&lv[4] = *(const float4*)(cs + kk + 4);
#pragma unroll
        for (int s = 0; s < 8; s++) lv[s] = __builtin_amdgcn_rcpf(lv[s]);

        s16x8 av[4], bv[4];
#pragma unroll
        for (int i = 0; i < 4; i++)
            av[i] = *(const s16x8*)(A + (size_t)(i * 16 + mr) * L_ + kk);
#pragma unroll
        for (int j = 0; j < 4; j++)
            bv[j] = *(const s16x8*)(Bb + (size_t)(j * 16 + mr) * L_ + kk);
        // scale e by 1/colsum[k] (per-k, pre-MFMA)
#pragma unroll
        for (int i = 0; i < 4; i++) {
            u16* u = (u16*)&av[i];
#pragma unroll
            for (int s = 0; s < 8; s++) u[s] = f2bf(bf2f(u[s]) * lv[s]);
        }
#pragma unroll
        for (int i = 0; i < 4; i++)
#pragma unroll
            for (int j = 0; j < 4; j++)
                acc[i][j] = __builtin_amdgcn_mfma_f32_16x16x32_bf16(av[i], bv[j], acc[i][j], 0, 0, 0);
    }

    __shared__ __align__(16) u16 T[128][136];
#pragma unroll
    for (int i = 0; i < 4; i++)
#pragma unroll
        for (int j = 0; j < 4; j++) {
            int col = wc * 64 + j * 16 + mr;
#pragma unroll
            for (int r = 0; r < 4; r++)
                T[wr * 64 + i * 16 + quad * 4 + r][col] = f2bf(acc[i][j][r]);
        }
    __syncthreads();
    {
        int t = threadIdx.x;
        const int wv = t >> 6, l = t & 63;
        const int col = (l & 15) * 8;
#pragma unroll
        for (int p = 0; p < 8; p++) {
            int row = p * 16 + wv * 4 + (l >> 4);
            u16* dst = att + ((size_t)n * L_ + q0 + row) * D_ + col;
            *(uint4*)dst = *(const uint4*)&T[row][col];
        }
    }
}

// ---------------------------------------------------------------
// K5: out = att_flat[8192][1024] @ Wo[128][1024]^T + bo.
// BM=32, BN=128, 4 waves (wave w: 32q x 32 cols, acc[2][2]), grid 256.
// ---------------------------------------------------------------
__global__ __launch_bounds__(256) void k5_out(
    const u16* __restrict__ att, const u16* __restrict__ Wob,
    const u16* __restrict__ bob, const int* __restrict__ flags,
    void* __restrict__ out) {
    const int dt = flags[0];
    const int m0 = blockIdx.x * 32;
    const int lane = threadIdx.x & 63, wave = threadIdx.x >> 6;
    const int mr = lane & 15, quad = lane >> 4;

    f32x4 acc[2][2];
#pragma unroll
    for (int i = 0; i < 2; i++)
#pragma unroll
        for (int j = 0; j < 2; j++) acc[i][j] = (f32x4){0.f, 0.f, 0.f, 0.f};

    const u16* A  = att + (size_t)m0 * HD_;
    const u16* Bw = Wob + (size_t)(wave * 32) * HD_;
    for (int k0 = 0; k0 < HD_; k0 += 32) {
        s16x8 av[2], bv[2];
#pragma unroll
        for (int i = 0; i < 2; i++)
            av[i] = *(const s16x8*)(A + (size_t)(i * 16 + mr) * HD_ + k0 + quad * 8);
#pragma unroll
        for (int j = 0; j < 2; j++)
            bv[j] = *(const s16x8*)(Bw + (size_t)(j * 16 + mr) * HD_ + k0 + quad * 8);
#pragma unroll
        for (int i = 0; i < 2; i++)
#pragma unroll
            for (int j = 0; j < 2; j++)
                acc[i][j] = __builtin_amdgcn_mfma_f32_16x16x32_bf16(av[i], bv[j], acc[i][j], 0, 0, 0);
    }

    __shared__ __align__(16) float Tf[32][132];
#pragma unroll
    for (int i = 0; i < 2; i++)
#pragma unroll
        for (int j = 0; j < 2; j++) {
            int col = wave * 32 + j * 16 + mr;
            float bv_ = bf2f(bob[col]);
#pragma unroll
            for (int r = 0; r < 4; r++)
                Tf[i * 16 + quad * 4 + r][col] = acc[i][j][r] + bv_;
        }
    __syncthreads();
    int t = threadIdx.x, row = t >> 3, cg = (t & 7) * 16;
    size_t base = (size_t)(m0 + row) * D_ + cg;
    if (dt) {
        u16* o = (u16*)out;
        u16 tmp[16];
#pragma unroll
        for (int s = 0; s < 16; s++) tmp[s] = f2bf(Tf[row][cg + s]);
        *(uint4*)(o + base)     = *(const uint4*)&tmp[0];
        *(uint4*)(o + base + 8) = *(const uint4*)&tmp[8];
    } else {
        float* o = (float*)out;
#pragma unroll
        for (int c = 0; c < 16; c += 4)
            *(float4*)(o + base + c) = *(const float4*)&Tf[row][cg + c];
    }
}

// ---------------------------------------------------------------
extern "C" void kernel_launch(void* const* d_in, const int* in_sizes, int n_in,
                              void* d_out, int out_size, void* d_ws, size_t ws_size,
                              hipStream_t stream) {
    (void)in_sizes; (void)n_in; (void)out_size; (void)ws_size;
    const void* x  = d_in[0];
    const void* Wq = d_in[1]; const void* bq = d_in[2];
    const void* Wk = d_in[3]; const void* bk = d_in[4];
    const void* Wv = d_in[5]; const void* bv = d_in[6];
    const void* Wo = d_in[7]; const void* bo = d_in[8];
    const void* pad = d_in[9];

    char* p = (char*)d_ws;
    auto alloc = [&](size_t bytes) { char* r = p; p += (bytes + 255) & ~(size_t)255; return r; };
    int*  flags = (int*)alloc(256);
    u16*  xb   = (u16*)alloc(2097152);
    u16*  Wqb  = (u16*)alloc(262144);
    u16*  Wkb  = (u16*)alloc(262144);
    u16*  Wvb  = (u16*)alloc(262144);
    u16*  Wob  = (u16*)alloc(262144);
    u16*  bqb  = (u16*)alloc(2048);
    u16*  bkb  = (u16*)alloc(2048);
    u16*  bvb  = (u16*)alloc(2048);
    u16*  bob  = (u16*)alloc(256);
    unsigned* mbits = (unsigned*)alloc(524288);
    float* colsum = (float*)alloc(262144);    // [128 n][512 k] fp32
    u16*  qb   = (u16*)alloc(16777216);
    u16*  kb   = (u16*)alloc(16777216);
    u16*  vtb  = (u16*)alloc(16777216);
    u16*  sb   = (u16*)alloc(67108864);
    u16*  att  = qb;   // alias: qb dead after k2; k4 writes disjoint q-rows

    k0_detect<<<1, 256, 0, stream>>>((const unsigned*)pad, (const unsigned*)x, flags);
    kprep_conv<<<(PREP_V + 255) / 256, 256, 0, stream>>>(
        x, Wq, bq, Wk, bk, Wv, bv, Wo, bo, flags,
        xb, Wqb, Wkb, Wvb, Wob, bqb, bkb, bvb, bob);
    kprep_mask<<<512, 256, 0, stream>>>(pad, flags, mbits, colsum);
    k1_proj<<<dim3(64, 8, 3), 256, 0, stream>>>(
        xb, Wqb, Wkb, Wvb, bqb, bkb, bvb, qb, kb, vtb);
    k2_scores<<<dim3(16, NH_), 256, 0, stream>>>(qb, kb, mbits, sb, colsum);
    k4_av<<<dim3(4, NH_), 256, 0, stream>>>(sb, vtb, colsum, att);
    k5_out<<<256, 256, 0, stream>>>(att, Wob, bob, flags, d_out);
}